// Round 2
// baseline (4892.092 us; speedup 1.0000x reference)
//
#include <hip/hip_runtime.h>

typedef __attribute__((ext_vector_type(4))) float f32x4;
typedef __attribute__((ext_vector_type(8))) short s16x8;
typedef __attribute__((ext_vector_type(4))) unsigned short u16x4;
typedef unsigned short u16;

// ---------- bf16 helpers (RNE) ----------
__device__ inline u16 f2bf(float x) {
  unsigned u = __float_as_uint(x);
  return (u16)((u + 0x7fffu + ((u >> 16) & 1u)) >> 16);
}
__device__ inline float bf2f(u16 h) {
  return __uint_as_float(((unsigned)h) << 16);
}

__device__ inline void glds16(const void* g, void* l) {
  __builtin_amdgcn_global_load_lds((const __attribute__((address_space(1))) void*)g,
                                   (__attribute__((address_space(3))) void*)l, 16, 0, 0);
}

// ---------- GEMM: C[M,N] = A[M,K] (bf16) @ (Wh+Wl)[N,K]^T (bf16 split) ----------
// m97 structure: 128-wide tiles, BK=32, global_load_lds width-16, linear LDS +
// source-side XOR k-chunk swizzle. 256 thr = 4 waves (2x2 wave grid).
// flags: 0 = fp32 out, 1 = fp32+bias, 2 = bf16 out, 3 = fp32 softplus(acc+bias)
template<int FM, int FN>
__global__ __launch_bounds__(256)
void gemm_bf(const u16* __restrict__ A, int lda,
             const u16* __restrict__ Wh, const u16* __restrict__ Wl, int ldw,
             void* __restrict__ Cv, int ldc, int K,
             const float* __restrict__ bias, int flags) {
  constexpr int BM = 32 * FM, BN = 32 * FN;
  __shared__ alignas(16) u16 lA[BM * 32];
  __shared__ alignas(16) u16 lWh[BN * 32];
  __shared__ alignas(16) u16 lWl[BN * 32];
  const int tid = threadIdx.x;
  const int m0 = blockIdx.y * BM, n0 = blockIdx.x * BN;
  const int wave = tid >> 6, lane = tid & 63;
  const int wr = (wave >> 1) * (16 * FM), wc = (wave & 1) * (16 * FN);
  const int fr = lane & 15, fq = lane >> 4;
  const int srow = lane >> 2, skc = lane & 3;
  f32x4 acc[FM][FN] = {};
  for (int k0 = 0; k0 < K; k0 += 32) {
    __syncthreads();
    // stage A: BM/16 chunks of 1KB; wave w owns chunks [w*FM/2, w*FM/2+FM/2)
    #pragma unroll
    for (int c = 0; c < FM / 2; ++c) {
      int ch = wave * (FM / 2) + c;
      int row = ch * 16 + srow;
      glds16(A + (size_t)(m0 + row) * lda + k0 + ((skc ^ (row & 3)) * 8), &lA[ch * 512]);
    }
    #pragma unroll
    for (int c = 0; c < FN / 2; ++c) {
      int ch = wave * (FN / 2) + c;
      int row = ch * 16 + srow;
      size_t go = (size_t)(n0 + row) * ldw + k0 + ((skc ^ (row & 3)) * 8);
      glds16(Wh + go, &lWh[ch * 512]);
      glds16(Wl + go, &lWl[ch * 512]);
    }
    __syncthreads();
    s16x8 af[FM], bh[FN], bl[FN];
    #pragma unroll
    for (int mi = 0; mi < FM; ++mi) {
      int r = wr + mi * 16 + fr;
      af[mi] = *reinterpret_cast<const s16x8*>(&lA[r * 32 + ((fq ^ (r & 3)) * 8)]);
    }
    #pragma unroll
    for (int ni = 0; ni < FN; ++ni) {
      int r = wc + ni * 16 + fr;
      int so = r * 32 + ((fq ^ (r & 3)) * 8);
      bh[ni] = *reinterpret_cast<const s16x8*>(&lWh[so]);
      bl[ni] = *reinterpret_cast<const s16x8*>(&lWl[so]);
    }
    #pragma unroll
    for (int mi = 0; mi < FM; ++mi)
      #pragma unroll
      for (int ni = 0; ni < FN; ++ni) {
        acc[mi][ni] = __builtin_amdgcn_mfma_f32_16x16x32_bf16(af[mi], bh[ni], acc[mi][ni], 0, 0, 0);
        acc[mi][ni] = __builtin_amdgcn_mfma_f32_16x16x32_bf16(af[mi], bl[ni], acc[mi][ni], 0, 0, 0);
      }
  }
  if (flags == 2) {
    u16* Cb = (u16*)Cv;
    #pragma unroll
    for (int mi = 0; mi < FM; ++mi)
      #pragma unroll
      for (int ni = 0; ni < FN; ++ni) {
        int gm = m0 + wr + mi * 16 + fq * 4;
        int gn = n0 + wc + ni * 16 + fr;
        #pragma unroll
        for (int r = 0; r < 4; ++r)
          Cb[(size_t)(gm + r) * ldc + gn] = f2bf(acc[mi][ni][r]);
      }
  } else {
    float* C = (float*)Cv;
    #pragma unroll
    for (int mi = 0; mi < FM; ++mi)
      #pragma unroll
      for (int ni = 0; ni < FN; ++ni) {
        int gm = m0 + wr + mi * 16 + fq * 4;
        int gn = n0 + wc + ni * 16 + fr;
        float badd = (flags == 1 || flags == 3) ? bias[gn] : 0.f;
        #pragma unroll
        for (int r = 0; r < 4; ++r) {
          float s = acc[mi][ni][r] + badd;
          if (flags == 3) s = (s > 20.f) ? s : log1pf(__expf(s));
          C[(size_t)(gm + r) * ldc + gn] = s;
        }
      }
  }
}

// ---------- weight conversion: fp32 -> bf16 hi/lo ----------
__global__ void k_wcvt(const float* __restrict__ s0, const float* __restrict__ s1,
                       const float* __restrict__ s2, const float* __restrict__ s3,
                       u16* __restrict__ wh, u16* __restrict__ wl) {
  int i4 = blockIdx.x * 256 + threadIdx.x;
  size_t idx = (size_t)i4 * 4;
  const float* s; size_t off;
  if (idx < 1048576)      { s = s0; off = idx; }
  else if (idx < 1572864) { s = s1; off = idx - 1048576; }
  else if (idx < 3670016) { s = s2; off = idx - 1572864; }
  else                    { s = s3; off = idx - 3670016; }
  f32x4 v = *reinterpret_cast<const f32x4*>(s + off);
  u16x4 hv, lv;
  #pragma unroll
  for (int j = 0; j < 4; ++j) {
    u16 hb = f2bf(v[j]);
    hv[j] = hb;
    lv[j] = f2bf(v[j] - bf2f(hb));
  }
  *reinterpret_cast<u16x4*>(wh + idx) = hv;
  *reinterpret_cast<u16x4*>(wl + idx) = lv;
}

__global__ void k_cvtsplit(const float* __restrict__ s, u16* __restrict__ wh, u16* __restrict__ wl) {
  int i4 = blockIdx.x * 256 + threadIdx.x;
  size_t idx = (size_t)i4 * 4;
  f32x4 v = *reinterpret_cast<const f32x4*>(s + idx);
  u16x4 hv, lv;
  #pragma unroll
  for (int j = 0; j < 4; ++j) {
    u16 hb = f2bf(v[j]);
    hv[j] = hb;
    lv[j] = f2bf(v[j] - bf2f(hb));
  }
  *reinterpret_cast<u16x4*>(wh + idx) = hv;
  *reinterpret_cast<u16x4*>(wl + idx) = lv;
}

__global__ void k_cvt(const float* __restrict__ s, u16* __restrict__ d) {
  int i4 = blockIdx.x * 256 + threadIdx.x;
  size_t idx = (size_t)i4 * 4;
  f32x4 v = *reinterpret_cast<const f32x4*>(s + idx);
  u16x4 o;
  #pragma unroll
  for (int j = 0; j < 4; ++j) o[j] = f2bf(v[j]);
  *reinterpret_cast<u16x4*>(d + idx) = o;
}

// ---------- fused dt weight: M[o][k] = sum_r dtw[o][r] * xpw_dt[r][k], hi/lo split ----------
__global__ void k_fusedt(const float* __restrict__ dtw, const float* __restrict__ xpw,
                         u16* __restrict__ mh, u16* __restrict__ ml) {
  int o = blockIdx.x, tid = threadIdx.x;
  __shared__ float lw[32];
  if (tid < 32) lw[tid] = dtw[o * 32 + tid];
  __syncthreads();
  float a[4] = {};
  for (int r = 0; r < 32; ++r) {
    f32x4 xv = *reinterpret_cast<const f32x4*>(xpw + (size_t)r * 1024 + tid * 4);
    float wv = lw[r];
    #pragma unroll
    for (int j = 0; j < 4; ++j) a[j] += wv * xv[j];
  }
  u16x4 hv, lv;
  #pragma unroll
  for (int j = 0; j < 4; ++j) {
    u16 hb = f2bf(a[j]);
    hv[j] = hb;
    lv[j] = f2bf(a[j] - bf2f(hb));
  }
  *reinterpret_cast<u16x4*>(mh + (size_t)o * 1024 + tid * 4) = hv;
  *reinterpret_cast<u16x4*>(ml + (size_t)o * 1024 + tid * 4) = lv;
}

// ---------- residual add + rmsnorm (writes fp32 resid + bf16 normed) ----------
__global__ void k_addnorm(float* __restrict__ r, const float* __restrict__ h,
                          const float* __restrict__ w, float* __restrict__ o,
                          u16* __restrict__ ob) {
  int t = blockIdx.x, tid = threadIdx.x;
  size_t base = (size_t)t * 512;
  float s0 = r[base + tid] + h[base + tid];
  float s1 = r[base + 256 + tid] + h[base + 256 + tid];
  float ss = s0 * s0 + s1 * s1;
  for (int m = 32; m; m >>= 1) ss += __shfl_xor(ss, m);
  __shared__ float red[4];
  if ((tid & 63) == 0) red[tid >> 6] = ss;
  __syncthreads();
  float tot = red[0] + red[1] + red[2] + red[3];
  float sc = rsqrtf(tot * (1.f / 512.f) + 1e-5f);
  r[base + tid] = s0;
  r[base + 256 + tid] = s1;
  float o0 = s0 * sc * w[tid], o1 = s1 * sc * w[tid + 256];
  o[base + tid] = o0;
  o[base + 256 + tid] = o1;
  ob[base + tid] = f2bf(o0);
  ob[base + 256 + tid] = f2bf(o1);
}

// ---------- causal depthwise conv (4 taps) + silu; fp32 + bf16 outputs ----------
__global__ void k_conv(const float* __restrict__ xz, const float* __restrict__ cw,
                       const float* __restrict__ cb, float* __restrict__ xc,
                       u16* __restrict__ xcb) {
  int idx = blockIdx.x * 256 + threadIdx.x;
  int t = idx >> 10, d = idx & 1023, l = t & 511;
  f32x4 w = *reinterpret_cast<const f32x4*>(cw + d * 4);
  float v = cb[d];
  #pragma unroll
  for (int j = 0; j < 4; ++j) {
    int lj = l - 3 + j;
    if (lj >= 0) v += w[j] * xz[(size_t)(t - 3 + j) * 2048 + d];
  }
  float s = v / (1.f + __expf(-v));
  xc[idx] = s;
  xcb[idx] = f2bf(s);
}

// ---------- x_proj (B,C only): xdb[T,32] = xc[T,1024] @ xpw[32:64,1024]^T ----------
__global__ void k_xdb(const float* __restrict__ xc, const float* __restrict__ xpw,
                      float* __restrict__ xdb) {
  __shared__ float lx[4][1024];
  int tid = threadIdx.x;
  int t0 = blockIdx.x * 4;
  #pragma unroll
  for (int q = 0; q < 4; ++q)
    *reinterpret_cast<f32x4*>(&lx[q][tid * 4]) =
        *reinterpret_cast<const f32x4*>(xc + (size_t)(t0 + q) * 1024 + tid * 4);
  __syncthreads();
  int o = tid >> 3, p = tid & 7;
  const float* wr = xpw + (size_t)(32 + o) * 1024 + p * 128;
  float a[4] = {0.f, 0.f, 0.f, 0.f};
  for (int kk = 0; kk < 128; kk += 4) {
    f32x4 w4 = *reinterpret_cast<const f32x4*>(wr + kk);
    #pragma unroll
    for (int tt = 0; tt < 4; ++tt) {
      f32x4 x4 = *reinterpret_cast<const f32x4*>(&lx[tt][p * 128 + kk]);
      a[tt] += w4[0] * x4[0] + w4[1] * x4[1] + w4[2] * x4[2] + w4[3] * x4[3];
    }
  }
  #pragma unroll
  for (int tt = 0; tt < 4; ++tt) {
    float v = a[tt];
    v += __shfl_xor(v, 1);
    v += __shfl_xor(v, 2);
    v += __shfl_xor(v, 4);
    if (p == 0) xdb[(size_t)(t0 + tt) * 32 + o] = v;
  }
}

// ---------- scan pass 1: per-chunk decay product P and local end-state H ----------
__global__ __launch_bounds__(256) void k_scan1(
    const float* __restrict__ dt, const float* __restrict__ xc,
    const float* __restrict__ xdb, const float* __restrict__ alog,
    float* __restrict__ sP, float* __restrict__ sH) {
  int bid = blockIdx.x;
  int b = bid >> 7, dg = (bid >> 3) & 15, c = bid & 7;
  int tid = threadIdx.x, dl = tid >> 2, sq = tid & 3;
  int d = dg * 64 + dl;
  int t0 = b * 512 + c * 64;
  __shared__ float ldt[16][64], lxc[16][64], lB[16][16];
  f32x4 al = *reinterpret_cast<const f32x4*>(alog + (size_t)d * 16 + sq * 4);
  float A[4], h[4] = {}, P[4] = {1.f, 1.f, 1.f, 1.f};
  #pragma unroll
  for (int j = 0; j < 4; ++j) A[j] = -__expf(al[j]);
  for (int tile = 0; tile < 4; ++tile) {
    int tt = t0 + tile * 16;
    __syncthreads();
    {
      int row = tid >> 4, f4 = (tid & 15) * 4;
      *reinterpret_cast<f32x4*>(&ldt[row][f4]) =
          *reinterpret_cast<const f32x4*>(dt + (size_t)(tt + row) * 1024 + dg * 64 + f4);
      *reinterpret_cast<f32x4*>(&lxc[row][f4]) =
          *reinterpret_cast<const f32x4*>(xc + (size_t)(tt + row) * 1024 + dg * 64 + f4);
    }
    if (tid < 64) {
      int row = tid >> 2, f4 = (tid & 3) * 4;
      *reinterpret_cast<f32x4*>(&lB[row][f4]) =
          *reinterpret_cast<const f32x4*>(xdb + (size_t)(tt + row) * 32 + f4);
    }
    __syncthreads();
    for (int lr = 0; lr < 16; ++lr) {
      float dtv = ldt[lr][dl];
      float dtx = dtv * lxc[lr][dl];
      f32x4 Bv = *reinterpret_cast<const f32x4*>(&lB[lr][sq * 4]);
      #pragma unroll
      for (int j = 0; j < 4; ++j) {
        float e = __expf(dtv * A[j]);
        h[j] = h[j] * e + dtx * Bv[j];
        P[j] *= e;
      }
    }
  }
  size_t base = ((size_t)(c * 4 + b) * 1024 + d) * 16 + sq * 4;
  *reinterpret_cast<f32x4*>(sP + base) = (f32x4){P[0], P[1], P[2], P[3]};
  *reinterpret_cast<f32x4*>(sH + base) = (f32x4){h[0], h[1], h[2], h[3]};
}

// ---------- scan pass 2: combine chunk states, replay emitting y, fuse D-skip + silu(z), bf16 out ----------
__global__ __launch_bounds__(256) void k_scan3(
    const float* __restrict__ dt, const float* __restrict__ xc,
    const float* __restrict__ xdb, const float* __restrict__ alog,
    const float* __restrict__ sP, const float* __restrict__ sH,
    const float* __restrict__ xz, const float* __restrict__ Dw,
    u16* __restrict__ ygb) {
  int bid = blockIdx.x;
  int b = bid >> 7, dg = (bid >> 3) & 15, c = bid & 7;
  int tid = threadIdx.x, dl = tid >> 2, sq = tid & 3;
  int d = dg * 64 + dl;
  int t0 = b * 512 + c * 64;
  __shared__ float ldt[16][64], lxc[16][64], lB[16][16], lC[16][16], ly[16][64];
  f32x4 al = *reinterpret_cast<const f32x4*>(alog + (size_t)d * 16 + sq * 4);
  float A[4], h[4] = {};
  #pragma unroll
  for (int j = 0; j < 4; ++j) A[j] = -__expf(al[j]);
  {
    size_t base = ((size_t)b * 1024 + d) * 16 + sq * 4;
    for (int cc = 0; cc < c; ++cc) {
      f32x4 Pp = *reinterpret_cast<const f32x4*>(sP + (size_t)cc * 65536 + base);
      f32x4 Hh = *reinterpret_cast<const f32x4*>(sH + (size_t)cc * 65536 + base);
      #pragma unroll
      for (int j = 0; j < 4; ++j) h[j] = Pp[j] * h[j] + Hh[j];
    }
  }
  for (int tile = 0; tile < 4; ++tile) {
    int tt = t0 + tile * 16;
    __syncthreads();
    {
      int row = tid >> 4, f4 = (tid & 15) * 4;
      *reinterpret_cast<f32x4*>(&ldt[row][f4]) =
          *reinterpret_cast<const f32x4*>(dt + (size_t)(tt + row) * 1024 + dg * 64 + f4);
      *reinterpret_cast<f32x4*>(&lxc[row][f4]) =
          *reinterpret_cast<const f32x4*>(xc + (size_t)(tt + row) * 1024 + dg * 64 + f4);
    }
    if (tid < 64) {
      int row = tid >> 2, f4 = (tid & 3) * 4;
      *reinterpret_cast<f32x4*>(&lB[row][f4]) =
          *reinterpret_cast<const f32x4*>(xdb + (size_t)(tt + row) * 32 + f4);
    } else if (tid < 128) {
      int t2 = tid - 64;
      int row = t2 >> 2, f4 = (t2 & 3) * 4;
      *reinterpret_cast<f32x4*>(&lC[row][f4]) =
          *reinterpret_cast<const f32x4*>(xdb + (size_t)(tt + row) * 32 + 16 + f4);
    }
    __syncthreads();
    for (int lr = 0; lr < 16; ++lr) {
      float dtv = ldt[lr][dl];
      float dtx = dtv * lxc[lr][dl];
      f32x4 Bv = *reinterpret_cast<const f32x4*>(&lB[lr][sq * 4]);
      f32x4 Cv = *reinterpret_cast<const f32x4*>(&lC[lr][sq * 4]);
      float py = 0.f;
      #pragma unroll
      for (int j = 0; j < 4; ++j) {
        float e = __expf(dtv * A[j]);
        h[j] = h[j] * e + dtx * Bv[j];
        py += h[j] * Cv[j];
      }
      py += __shfl_xor(py, 1);
      py += __shfl_xor(py, 2);
      if (sq == 0) ly[lr][dl] = py;
    }
    __syncthreads();
    {
      int row = tid >> 4, f4 = (tid & 15) * 4;
      f32x4 y4 = *reinterpret_cast<f32x4*>(&ly[row][f4]);
      f32x4 x4 = *reinterpret_cast<f32x4*>(&lxc[row][f4]);
      f32x4 z4 = *reinterpret_cast<const f32x4*>(xz + (size_t)(tt + row) * 2048 + 1024 + dg * 64 + f4);
      f32x4 D4 = *reinterpret_cast<const f32x4*>(Dw + dg * 64 + f4);
      u16x4 o;
      #pragma unroll
      for (int j = 0; j < 4; ++j) {
        float yv = y4[j] + x4[j] * D4[j];
        float zz = z4[j];
        float g = zz / (1.f + __expf(-zz));
        o[j] = f2bf(yv * g);
      }
      *reinterpret_cast<u16x4*>(ygb + (size_t)(tt + row) * 1024 + dg * 64 + f4) = o;
    }
  }
}

// ---------- GLU: ml = y * silu(gate) (bf16 in/out) ----------
__global__ void k_glu_bf(const u16* __restrict__ fgb, u16* __restrict__ mlb) {
  int i4 = blockIdx.x * 256 + threadIdx.x;
  int t = i4 >> 9, n4 = (i4 & 511) * 4;
  u16x4 ya = *reinterpret_cast<const u16x4*>(fgb + (size_t)t * 4096 + n4);
  u16x4 ga = *reinterpret_cast<const u16x4*>(fgb + (size_t)t * 4096 + 2048 + n4);
  u16x4 o;
  #pragma unroll
  for (int j = 0; j < 4; ++j) {
    float y = bf2f(ya[j]), g = bf2f(ga[j]);
    float s = g / (1.f + __expf(-g));
    o[j] = f2bf(y * s);
  }
  *reinterpret_cast<u16x4*>(mlb + (size_t)t * 2048 + n4) = o;
}

// ---------- mean pool (2-stage) + head ----------
__global__ void k_pool1(const float* __restrict__ xn, float* __restrict__ part) {
  int b = blockIdx.x >> 4, lc = blockIdx.x & 15;
  int tid = threadIdx.x;
  float s0 = 0.f, s1 = 0.f;
  for (int l = lc * 32; l < lc * 32 + 32; ++l) {
    const float* row = xn + (size_t)(b * 512 + l) * 512;
    s0 += row[tid];
    s1 += row[tid + 256];
  }
  part[(size_t)blockIdx.x * 512 + tid] = s0;
  part[(size_t)blockIdx.x * 512 + tid + 256] = s1;
}

__global__ void k_pool2(const float* __restrict__ part, float* __restrict__ pooled) {
  int idx = blockIdx.x * 256 + threadIdx.x;
  int b = idx >> 9, dm = idx & 511;
  float s = 0.f;
  for (int lc = 0; lc < 16; ++lc) s += part[(size_t)(b * 16 + lc) * 512 + dm];
  pooled[idx] = s * (1.f / 512.f);
}

__global__ void k_head(const float* __restrict__ pooled, const float* __restrict__ hw,
                       const float* __restrict__ hb, float* __restrict__ out) {
  int b = blockIdx.x / 50, c = blockIdx.x % 50;
  int lane = threadIdx.x;
  float s = 0.f;
  #pragma unroll
  for (int q = 0; q < 8; ++q) {
    int dm = q * 64 + lane;
    s += pooled[b * 512 + dm] * hw[(size_t)c * 512 + dm];
  }
  for (int m = 32; m; m >>= 1) s += __shfl_xor(s, m);
  if (lane == 0) out[b * 50 + c] = s + hb[c];
}

// ---------- launch ----------
extern "C" void kernel_launch(void* const* d_in, const int* in_sizes, int n_in,
                              void* d_out, int out_size, void* d_ws, size_t ws_size,
                              hipStream_t stream) {
  (void)in_sizes; (void)n_in; (void)out_size; (void)ws_size;
  const float* x      = (const float*)d_in[0];
  const float* emb_w  = (const float*)d_in[1];
  const float* emb_b  = (const float*)d_in[2];
  const float* inp_w  = (const float*)d_in[3];
  const float* conv_w = (const float*)d_in[4];
  const float* conv_b = (const float*)d_in[5];
  const float* xp_w   = (const float*)d_in[6];
  const float* dt_w   = (const float*)d_in[7];
  const float* dt_b   = (const float*)d_in[8];
  const float* a_log  = (const float*)d_in[9];
  const float* Dw     = (const float*)d_in[10];
  const float* outp_w = (const float*)d_in[11];
  const float* n1_w   = (const float*)d_in[12];
  const float* n2_w   = (const float*)d_in[13];
  const float* fc1_w  = (const float*)d_in[14];
  const float* fc2_w  = (const float*)d_in[15];
  const float* nf_w   = (const float*)d_in[16];
  const float* head_w = (const float*)d_in[17];
  const float* head_b = (const float*)d_in[18];

  float* fp = (float*)d_ws;
  float* resid  = fp;
  float* hid    = fp + 1048576;
  float* xn     = fp + 2097152;
  float* xz     = fp + 3145728;   // T x 2048
  float* xc     = fp + 7340032;   // T x 1024
  float* dtbuf  = fp + 9437184;   // T x 1024
  float* xdb    = fp + 11534336;  // T x 32 (B|C)
  float* sP     = fp + 11665408;  // 8 x 4 x 1024 x 16
  float* sH     = fp + 12189696;
  float* part   = fp + 12713984;
  float* pooled = fp + 12746752;
  u16* us  = (u16*)(fp + 12748800);
  u16* fgb = us;                  // T x 4096
  u16* xb  = us + 8388608;        // T x 128
  u16* xnb = us + 8650752;        // T x 512
  u16* ygb = us + 9699328;        // T x 1024
  u16* mlb = us + 11796480;       // T x 2048
  u16* xcb = us + 15990784;       // T x 1024
  u16* wbh = us + 18087936;       // 5767168: inp|outp|fc1|fc2|M
  u16* wbl = us + 23855104;

  const int O_OUTP = 1048576, O_FC1 = 1572864, O_FC2 = 3670016, O_M = 4718592;

  hipMemsetAsync(resid, 0, (size_t)1048576 * 4, stream);
  k_cvt<<<256, 256, 0, stream>>>(x, xb);
  k_cvtsplit<<<64, 256, 0, stream>>>(emb_w, wbh, wbl);
  gemm_bf<4, 2><<<dim3(8, 16), 256, 0, stream>>>(xb, 128, wbh, wbl, 128, (void*)hid, 512, 128, emb_b, 1);

  for (int i = 0; i < 12; ++i) {
    k_wcvt<<<4608, 256, 0, stream>>>(inp_w + (size_t)i * 1048576, outp_w + (size_t)i * 524288,
                                     fc1_w + (size_t)i * 2097152, fc2_w + (size_t)i * 1048576,
                                     wbh, wbl);
    k_fusedt<<<1024, 256, 0, stream>>>(dt_w + (size_t)i * 32768, xp_w + (size_t)i * 65536,
                                       wbh + O_M, wbl + O_M);
    k_addnorm<<<2048, 256, 0, stream>>>(resid, hid, n1_w + i * 512, xn, xnb);
    gemm_bf<4, 4><<<dim3(16, 16), 256, 0, stream>>>(xnb, 512, wbh, wbl, 512,
                                                    (void*)xz, 2048, 512, nullptr, 0);
    k_conv<<<8192, 256, 0, stream>>>(xz, conv_w + (size_t)i * 4096, conv_b + i * 1024, xc, xcb);
    k_xdb<<<512, 256, 0, stream>>>(xc, xp_w + (size_t)i * 65536, xdb);
    gemm_bf<4, 4><<<dim3(8, 16), 256, 0, stream>>>(xcb, 1024, wbh + O_M, wbl + O_M, 1024,
                                                   (void*)dtbuf, 1024, 1024, dt_b + i * 1024, 3);
    k_scan1<<<512, 256, 0, stream>>>(dtbuf, xc, xdb, a_log + (size_t)i * 16384, sP, sH);
    k_scan3<<<512, 256, 0, stream>>>(dtbuf, xc, xdb, a_log + (size_t)i * 16384, sP, sH,
                                     xz, Dw + i * 1024, ygb);
    gemm_bf<4, 2><<<dim3(8, 16), 256, 0, stream>>>(ygb, 1024, wbh + O_OUTP, wbl + O_OUTP, 1024,
                                                   (void*)hid, 512, 1024, nullptr, 0);
    k_addnorm<<<2048, 256, 0, stream>>>(resid, hid, n2_w + i * 512, xn, xnb);
    gemm_bf<4, 4><<<dim3(32, 16), 256, 0, stream>>>(xnb, 512, wbh + O_FC1, wbl + O_FC1, 512,
                                                    (void*)fgb, 4096, 512, nullptr, 2);
    k_glu_bf<<<4096, 256, 0, stream>>>(fgb, mlb);
    gemm_bf<4, 2><<<dim3(8, 16), 256, 0, stream>>>(mlb, 2048, wbh + O_FC2, wbl + O_FC2, 2048,
                                                   (void*)hid, 512, 2048, nullptr, 0);
  }

  k_addnorm<<<2048, 256, 0, stream>>>(resid, hid, nf_w, xn, xnb);
  k_pool1<<<64, 256, 0, stream>>>(xn, part);
  k_pool2<<<8, 256, 0, stream>>>(part, pooled);
  k_head<<<200, 64, 0, stream>>>(pooled, head_w, head_b, (float*)d_out);
}

// Round 3
// 2543.528 us; speedup vs baseline: 1.9233x; 1.9233x over previous
//
#include <hip/hip_runtime.h>

typedef __attribute__((ext_vector_type(4))) float f32x4;
typedef __attribute__((ext_vector_type(8))) short s16x8;
typedef __attribute__((ext_vector_type(4))) unsigned short u16x4;
typedef unsigned short u16;

// ---------- bf16 helpers (RNE) ----------
__device__ inline u16 f2bf(float x) {
  unsigned u = __float_as_uint(x);
  return (u16)((u + 0x7fffu + ((u >> 16) & 1u)) >> 16);
}
__device__ inline float bf2f(u16 h) {
  return __uint_as_float(((unsigned)h) << 16);
}

__device__ inline void glds16(const void* g, void* l) {
  __builtin_amdgcn_global_load_lds((const __attribute__((address_space(1))) void*)g,
                                   (__attribute__((address_space(3))) void*)l, 16, 0, 0);
}

// ---------- GEMM: C[M,N] = A[M,K] (bf16) @ (Wh+Wl)[N,K]^T (bf16 split) ----------
// m97 structure: BK=32, global_load_lds w16, linear LDS + source-side XOR chunk swizzle.
// 256 thr = 4 waves (2x2). flags: 0=fp32, 1=fp32+bias, 2=bf16,
// 3 = dt epilogue: col<1024 -> softplus(acc+bias)->C (ldc), col in [1024,1056) -> fp32 aux (ld 32)
template<int FM, int FN>
__global__ __launch_bounds__(256)
void gemm_bf(const u16* __restrict__ A, int lda,
             const u16* __restrict__ Wh, const u16* __restrict__ Wl, int ldw,
             void* __restrict__ Cv, int ldc, int K,
             const float* __restrict__ bias, float* __restrict__ aux, int flags) {
  constexpr int BM = 32 * FM, BN = 32 * FN;
  __shared__ alignas(16) u16 lA[BM * 32];
  __shared__ alignas(16) u16 lWh[BN * 32];
  __shared__ alignas(16) u16 lWl[BN * 32];
  const int tid = threadIdx.x;
  const int m0 = blockIdx.y * BM, n0 = blockIdx.x * BN;
  const int wave = tid >> 6, lane = tid & 63;
  const int wr = (wave >> 1) * (16 * FM), wc = (wave & 1) * (16 * FN);
  const int fr = lane & 15, fq = lane >> 4;
  const int srow = lane >> 2, skc = lane & 3;
  f32x4 acc[FM][FN] = {};
  for (int k0 = 0; k0 < K; k0 += 32) {
    __syncthreads();
    #pragma unroll
    for (int c = 0; c < FM / 2; ++c) {
      int ch = wave * (FM / 2) + c;
      int row = ch * 16 + srow;
      glds16(A + (size_t)(m0 + row) * lda + k0 + ((skc ^ (row & 3)) * 8), &lA[ch * 512]);
    }
    #pragma unroll
    for (int c = 0; c < FN / 2; ++c) {
      int ch = wave * (FN / 2) + c;
      int row = ch * 16 + srow;
      size_t go = (size_t)(n0 + row) * ldw + k0 + ((skc ^ (row & 3)) * 8);
      glds16(Wh + go, &lWh[ch * 512]);
      glds16(Wl + go, &lWl[ch * 512]);
    }
    __syncthreads();
    s16x8 af[FM], bh[FN], bl[FN];
    #pragma unroll
    for (int mi = 0; mi < FM; ++mi) {
      int r = wr + mi * 16 + fr;
      af[mi] = *reinterpret_cast<const s16x8*>(&lA[r * 32 + ((fq ^ (r & 3)) * 8)]);
    }
    #pragma unroll
    for (int ni = 0; ni < FN; ++ni) {
      int r = wc + ni * 16 + fr;
      int so = r * 32 + ((fq ^ (r & 3)) * 8);
      bh[ni] = *reinterpret_cast<const s16x8*>(&lWh[so]);
      bl[ni] = *reinterpret_cast<const s16x8*>(&lWl[so]);
    }
    #pragma unroll
    for (int mi = 0; mi < FM; ++mi)
      #pragma unroll
      for (int ni = 0; ni < FN; ++ni) {
        acc[mi][ni] = __builtin_amdgcn_mfma_f32_16x16x32_bf16(af[mi], bh[ni], acc[mi][ni], 0, 0, 0);
        acc[mi][ni] = __builtin_amdgcn_mfma_f32_16x16x32_bf16(af[mi], bl[ni], acc[mi][ni], 0, 0, 0);
      }
  }
  if (flags == 2) {
    u16* Cb = (u16*)Cv;
    #pragma unroll
    for (int mi = 0; mi < FM; ++mi)
      #pragma unroll
      for (int ni = 0; ni < FN; ++ni) {
        int gm = m0 + wr + mi * 16 + fq * 4;
        int gn = n0 + wc + ni * 16 + fr;
        #pragma unroll
        for (int r = 0; r < 4; ++r)
          Cb[(size_t)(gm + r) * ldc + gn] = f2bf(acc[mi][ni][r]);
      }
  } else if (flags == 3) {
    float* C = (float*)Cv;
    #pragma unroll
    for (int mi = 0; mi < FM; ++mi)
      #pragma unroll
      for (int ni = 0; ni < FN; ++ni) {
        int gm = m0 + wr + mi * 16 + fq * 4;
        int gn = n0 + wc + ni * 16 + fr;
        if (gn < 1024) {
          float badd = bias[gn];
          #pragma unroll
          for (int r = 0; r < 4; ++r) {
            float s = acc[mi][ni][r] + badd;
            s = (s > 20.f) ? s : log1pf(__expf(s));
            C[(size_t)(gm + r) * ldc + gn] = s;
          }
        } else if (gn < 1056) {
          #pragma unroll
          for (int r = 0; r < 4; ++r)
            aux[(size_t)(gm + r) * 32 + (gn - 1024)] = acc[mi][ni][r];
        }
      }
  } else {
    float* C = (float*)Cv;
    #pragma unroll
    for (int mi = 0; mi < FM; ++mi)
      #pragma unroll
      for (int ni = 0; ni < FN; ++ni) {
        int gm = m0 + wr + mi * 16 + fq * 4;
        int gn = n0 + wc + ni * 16 + fr;
        float badd = (flags == 1) ? bias[gn] : 0.f;
        #pragma unroll
        for (int r = 0; r < 4; ++r)
          C[(size_t)(gm + r) * ldc + gn] = acc[mi][ni][r] + badd;
      }
  }
}

// ---------- weight conversion: fp32 -> bf16 hi/lo ----------
__global__ void k_wcvt(const float* __restrict__ s0, const float* __restrict__ s1,
                       const float* __restrict__ s2, const float* __restrict__ s3,
                       u16* __restrict__ wh, u16* __restrict__ wl) {
  int i4 = blockIdx.x * 256 + threadIdx.x;
  size_t idx = (size_t)i4 * 4;
  const float* s; size_t off;
  if (idx < 1048576)      { s = s0; off = idx; }
  else if (idx < 1572864) { s = s1; off = idx - 1048576; }
  else if (idx < 3670016) { s = s2; off = idx - 1572864; }
  else                    { s = s3; off = idx - 3670016; }
  f32x4 v = *reinterpret_cast<const f32x4*>(s + off);
  u16x4 hv, lv;
  #pragma unroll
  for (int j = 0; j < 4; ++j) {
    u16 hb = f2bf(v[j]);
    hv[j] = hb;
    lv[j] = f2bf(v[j] - bf2f(hb));
  }
  *reinterpret_cast<u16x4*>(wh + idx) = hv;
  *reinterpret_cast<u16x4*>(wl + idx) = lv;
}

__global__ void k_cvtsplit(const float* __restrict__ s, u16* __restrict__ wh, u16* __restrict__ wl) {
  int i4 = blockIdx.x * 256 + threadIdx.x;
  size_t idx = (size_t)i4 * 4;
  f32x4 v = *reinterpret_cast<const f32x4*>(s + idx);
  u16x4 hv, lv;
  #pragma unroll
  for (int j = 0; j < 4; ++j) {
    u16 hb = f2bf(v[j]);
    hv[j] = hb;
    lv[j] = f2bf(v[j] - bf2f(hb));
  }
  *reinterpret_cast<u16x4*>(wh + idx) = hv;
  *reinterpret_cast<u16x4*>(wl + idx) = lv;
}

__global__ void k_cvt(const float* __restrict__ s, u16* __restrict__ d) {
  int i4 = blockIdx.x * 256 + threadIdx.x;
  size_t idx = (size_t)i4 * 4;
  f32x4 v = *reinterpret_cast<const f32x4*>(s + idx);
  u16x4 o;
  #pragma unroll
  for (int j = 0; j < 4; ++j) o[j] = f2bf(v[j]);
  *reinterpret_cast<u16x4*>(d + idx) = o;
}

// ---------- dt+BC extended weight: rows 0..1023 = dtw@xpw_dt fused; 1024..1055 = xpw B,C; 1056..1087 = 0 ----------
__global__ void k_dtbcw(const float* __restrict__ dtw, const float* __restrict__ xpw,
                        u16* __restrict__ mh, u16* __restrict__ ml) {
  int o = blockIdx.x, tid = threadIdx.x;
  float a[4] = {};
  if (o < 1024) {
    __shared__ float lw[32];
    if (tid < 32) lw[tid] = dtw[o * 32 + tid];
    __syncthreads();
    for (int r = 0; r < 32; ++r) {
      f32x4 xv = *reinterpret_cast<const f32x4*>(xpw + (size_t)r * 1024 + tid * 4);
      float wv = lw[r];
      #pragma unroll
      for (int j = 0; j < 4; ++j) a[j] += wv * xv[j];
    }
  } else if (o < 1056) {
    f32x4 xv = *reinterpret_cast<const f32x4*>(xpw + (size_t)(o - 1024 + 32) * 1024 + tid * 4);
    #pragma unroll
    for (int j = 0; j < 4; ++j) a[j] = xv[j];
  }
  u16x4 hv, lv;
  #pragma unroll
  for (int j = 0; j < 4; ++j) {
    u16 hb = f2bf(a[j]);
    hv[j] = hb;
    lv[j] = f2bf(a[j] - bf2f(hb));
  }
  *reinterpret_cast<u16x4*>(mh + (size_t)o * 1024 + tid * 4) = hv;
  *reinterpret_cast<u16x4*>(ml + (size_t)o * 1024 + tid * 4) = lv;
}

// ---------- residual add + rmsnorm (writes fp32 resid + bf16 normed) ----------
__global__ void k_addnorm(float* __restrict__ r, const float* __restrict__ h,
                          const float* __restrict__ w, float* __restrict__ o,
                          u16* __restrict__ ob) {
  int t = blockIdx.x, tid = threadIdx.x;
  size_t base = (size_t)t * 512;
  float s0 = r[base + tid] + h[base + tid];
  float s1 = r[base + 256 + tid] + h[base + 256 + tid];
  float ss = s0 * s0 + s1 * s1;
  for (int m = 32; m; m >>= 1) ss += __shfl_xor(ss, m);
  __shared__ float red[4];
  if ((tid & 63) == 0) red[tid >> 6] = ss;
  __syncthreads();
  float tot = red[0] + red[1] + red[2] + red[3];
  float sc = rsqrtf(tot * (1.f / 512.f) + 1e-5f);
  r[base + tid] = s0;
  r[base + 256 + tid] = s1;
  float o0 = s0 * sc * w[tid], o1 = s1 * sc * w[tid + 256];
  o[base + tid] = o0;
  o[base + 256 + tid] = o1;
  ob[base + tid] = f2bf(o0);
  ob[base + 256 + tid] = f2bf(o1);
}

// ---------- causal depthwise conv (4 taps) + silu; fp32 + bf16 outputs ----------
__global__ void k_conv(const float* __restrict__ xz, const float* __restrict__ cw,
                       const float* __restrict__ cb, float* __restrict__ xc,
                       u16* __restrict__ xcb) {
  int idx = blockIdx.x * 256 + threadIdx.x;
  int t = idx >> 10, d = idx & 1023, l = t & 511;
  f32x4 w = *reinterpret_cast<const f32x4*>(cw + d * 4);
  float v = cb[d];
  #pragma unroll
  for (int j = 0; j < 4; ++j) {
    int lj = l - 3 + j;
    if (lj >= 0) v += w[j] * xz[(size_t)(t - 3 + j) * 2048 + d];
  }
  float s = v / (1.f + __expf(-v));
  xc[idx] = s;
  xcb[idx] = f2bf(s);
}

// ---------- scan pass 1: per-chunk decay product P and local end-state H ----------
__global__ __launch_bounds__(256) void k_scan1(
    const float* __restrict__ dt, const float* __restrict__ xc,
    const float* __restrict__ xdb, const float* __restrict__ alog,
    float* __restrict__ sP, float* __restrict__ sH) {
  int bid = blockIdx.x;
  int b = bid >> 7, dg = (bid >> 3) & 15, c = bid & 7;
  int tid = threadIdx.x, dl = tid >> 2, sq = tid & 3;
  int d = dg * 64 + dl;
  int t0 = b * 512 + c * 64;
  __shared__ float ldt[16][64], lxc[16][64], lB[16][16];
  f32x4 al = *reinterpret_cast<const f32x4*>(alog + (size_t)d * 16 + sq * 4);
  float A[4], h[4] = {}, P[4] = {1.f, 1.f, 1.f, 1.f};
  #pragma unroll
  for (int j = 0; j < 4; ++j) A[j] = -__expf(al[j]);
  for (int tile = 0; tile < 4; ++tile) {
    int tt = t0 + tile * 16;
    __syncthreads();
    {
      int row = tid >> 4, f4 = (tid & 15) * 4;
      *reinterpret_cast<f32x4*>(&ldt[row][f4]) =
          *reinterpret_cast<const f32x4*>(dt + (size_t)(tt + row) * 1024 + dg * 64 + f4);
      *reinterpret_cast<f32x4*>(&lxc[row][f4]) =
          *reinterpret_cast<const f32x4*>(xc + (size_t)(tt + row) * 1024 + dg * 64 + f4);
    }
    if (tid < 64) {
      int row = tid >> 2, f4 = (tid & 3) * 4;
      *reinterpret_cast<f32x4*>(&lB[row][f4]) =
          *reinterpret_cast<const f32x4*>(xdb + (size_t)(tt + row) * 32 + f4);
    }
    __syncthreads();
    for (int lr = 0; lr < 16; ++lr) {
      float dtv = ldt[lr][dl];
      float dtx = dtv * lxc[lr][dl];
      f32x4 Bv = *reinterpret_cast<const f32x4*>(&lB[lr][sq * 4]);
      #pragma unroll
      for (int j = 0; j < 4; ++j) {
        float e = __expf(dtv * A[j]);
        h[j] = h[j] * e + dtx * Bv[j];
        P[j] *= e;
      }
    }
  }
  size_t base = ((size_t)(c * 4 + b) * 1024 + d) * 16 + sq * 4;
  *reinterpret_cast<f32x4*>(sP + base) = (f32x4){P[0], P[1], P[2], P[3]};
  *reinterpret_cast<f32x4*>(sH + base) = (f32x4){h[0], h[1], h[2], h[3]};
}

// ---------- scan pass 2: combine chunk states, replay, fuse D-skip + silu(z), bf16 out ----------
__global__ __launch_bounds__(256) void k_scan3(
    const float* __restrict__ dt, const float* __restrict__ xc,
    const float* __restrict__ xdb, const float* __restrict__ alog,
    const float* __restrict__ sP, const float* __restrict__ sH,
    const float* __restrict__ xz, const float* __restrict__ Dw,
    u16* __restrict__ ygb) {
  int bid = blockIdx.x;
  int b = bid >> 7, dg = (bid >> 3) & 15, c = bid & 7;
  int tid = threadIdx.x, dl = tid >> 2, sq = tid & 3;
  int d = dg * 64 + dl;
  int t0 = b * 512 + c * 64;
  __shared__ float ldt[16][64], lxc[16][64], lB[16][16], lC[16][16], ly[16][64];
  f32x4 al = *reinterpret_cast<const f32x4*>(alog + (size_t)d * 16 + sq * 4);
  float A[4], h[4] = {};
  #pragma unroll
  for (int j = 0; j < 4; ++j) A[j] = -__expf(al[j]);
  {
    size_t base = ((size_t)b * 1024 + d) * 16 + sq * 4;
    for (int cc = 0; cc < c; ++cc) {
      f32x4 Pp = *reinterpret_cast<const f32x4*>(sP + (size_t)cc * 65536 + base);
      f32x4 Hh = *reinterpret_cast<const f32x4*>(sH + (size_t)cc * 65536 + base);
      #pragma unroll
      for (int j = 0; j < 4; ++j) h[j] = Pp[j] * h[j] + Hh[j];
    }
  }
  for (int tile = 0; tile < 4; ++tile) {
    int tt = t0 + tile * 16;
    __syncthreads();
    {
      int row = tid >> 4, f4 = (tid & 15) * 4;
      *reinterpret_cast<f32x4*>(&ldt[row][f4]) =
          *reinterpret_cast<const f32x4*>(dt + (size_t)(tt + row) * 1024 + dg * 64 + f4);
      *reinterpret_cast<f32x4*>(&lxc[row][f4]) =
          *reinterpret_cast<const f32x4*>(xc + (size_t)(tt + row) * 1024 + dg * 64 + f4);
    }
    if (tid < 64) {
      int row = tid >> 2, f4 = (tid & 3) * 4;
      *reinterpret_cast<f32x4*>(&lB[row][f4]) =
          *reinterpret_cast<const f32x4*>(xdb + (size_t)(tt + row) * 32 + f4);
    } else if (tid < 128) {
      int t2 = tid - 64;
      int row = t2 >> 2, f4 = (t2 & 3) * 4;
      *reinterpret_cast<f32x4*>(&lC[row][f4]) =
          *reinterpret_cast<const f32x4*>(xdb + (size_t)(tt + row) * 32 + 16 + f4);
    }
    __syncthreads();
    for (int lr = 0; lr < 16; ++lr) {
      float dtv = ldt[lr][dl];
      float dtx = dtv * lxc[lr][dl];
      f32x4 Bv = *reinterpret_cast<const f32x4*>(&lB[lr][sq * 4]);
      f32x4 Cv = *reinterpret_cast<const f32x4*>(&lC[lr][sq * 4]);
      float py = 0.f;
      #pragma unroll
      for (int j = 0; j < 4; ++j) {
        float e = __expf(dtv * A[j]);
        h[j] = h[j] * e + dtx * Bv[j];
        py += h[j] * Cv[j];
      }
      py += __shfl_xor(py, 1);
      py += __shfl_xor(py, 2);
      if (sq == 0) ly[lr][dl] = py;
    }
    __syncthreads();
    {
      int row = tid >> 4, f4 = (tid & 15) * 4;
      f32x4 y4 = *reinterpret_cast<f32x4*>(&ly[row][f4]);
      f32x4 x4 = *reinterpret_cast<f32x4*>(&lxc[row][f4]);
      f32x4 z4 = *reinterpret_cast<const f32x4*>(xz + (size_t)(tt + row) * 2048 + 1024 + dg * 64 + f4);
      f32x4 D4 = *reinterpret_cast<const f32x4*>(Dw + dg * 64 + f4);
      u16x4 o;
      #pragma unroll
      for (int j = 0; j < 4; ++j) {
        float yv = y4[j] + x4[j] * D4[j];
        float zz = z4[j];
        float g = zz / (1.f + __expf(-zz));
        o[j] = f2bf(yv * g);
      }
      *reinterpret_cast<u16x4*>(ygb + (size_t)(tt + row) * 1024 + dg * 64 + f4) = o;
    }
  }
}

// ---------- GLU: ml = y * silu(gate) (bf16 in/out) ----------
__global__ void k_glu_bf(const u16* __restrict__ fgb, u16* __restrict__ mlb) {
  int i4 = blockIdx.x * 256 + threadIdx.x;
  int t = i4 >> 9, n4 = (i4 & 511) * 4;
  u16x4 ya = *reinterpret_cast<const u16x4*>(fgb + (size_t)t * 4096 + n4);
  u16x4 ga = *reinterpret_cast<const u16x4*>(fgb + (size_t)t * 4096 + 2048 + n4);
  u16x4 o;
  #pragma unroll
  for (int j = 0; j < 4; ++j) {
    float y = bf2f(ya[j]), g = bf2f(ga[j]);
    float s = g / (1.f + __expf(-g));
    o[j] = f2bf(y * s);
  }
  *reinterpret_cast<u16x4*>(mlb + (size_t)t * 2048 + n4) = o;
}

// ---------- mean pool (2-stage) + head ----------
__global__ void k_pool1(const float* __restrict__ xn, float* __restrict__ part) {
  int b = blockIdx.x >> 4, lc = blockIdx.x & 15;
  int tid = threadIdx.x;
  float s0 = 0.f, s1 = 0.f;
  for (int l = lc * 32; l < lc * 32 + 32; ++l) {
    const float* row = xn + (size_t)(b * 512 + l) * 512;
    s0 += row[tid];
    s1 += row[tid + 256];
  }
  part[(size_t)blockIdx.x * 512 + tid] = s0;
  part[(size_t)blockIdx.x * 512 + tid + 256] = s1;
}

__global__ void k_pool2(const float* __restrict__ part, float* __restrict__ pooled) {
  int idx = blockIdx.x * 256 + threadIdx.x;
  int b = idx >> 9, dm = idx & 511;
  float s = 0.f;
  for (int lc = 0; lc < 16; ++lc) s += part[(size_t)(b * 16 + lc) * 512 + dm];
  pooled[idx] = s * (1.f / 512.f);
}

__global__ void k_head(const float* __restrict__ pooled, const float* __restrict__ hw,
                       const float* __restrict__ hb, float* __restrict__ out) {
  int b = blockIdx.x / 50, c = blockIdx.x % 50;
  int lane = threadIdx.x;
  float s = 0.f;
  #pragma unroll
  for (int q = 0; q < 8; ++q) {
    int dm = q * 64 + lane;
    s += pooled[b * 512 + dm] * hw[(size_t)c * 512 + dm];
  }
  for (int m = 32; m; m >>= 1) s += __shfl_xor(s, m);
  if (lane == 0) out[b * 50 + c] = s + hb[c];
}

// ---------- launch ----------
extern "C" void kernel_launch(void* const* d_in, const int* in_sizes, int n_in,
                              void* d_out, int out_size, void* d_ws, size_t ws_size,
                              hipStream_t stream) {
  (void)in_sizes; (void)n_in; (void)out_size; (void)ws_size;
  const float* x      = (const float*)d_in[0];
  const float* emb_w  = (const float*)d_in[1];
  const float* emb_b  = (const float*)d_in[2];
  const float* inp_w  = (const float*)d_in[3];
  const float* conv_w = (const float*)d_in[4];
  const float* conv_b = (const float*)d_in[5];
  const float* xp_w   = (const float*)d_in[6];
  const float* dt_w   = (const float*)d_in[7];
  const float* dt_b   = (const float*)d_in[8];
  const float* a_log  = (const float*)d_in[9];
  const float* Dw     = (const float*)d_in[10];
  const float* outp_w = (const float*)d_in[11];
  const float* n1_w   = (const float*)d_in[12];
  const float* n2_w   = (const float*)d_in[13];
  const float* fc1_w  = (const float*)d_in[14];
  const float* fc2_w  = (const float*)d_in[15];
  const float* nf_w   = (const float*)d_in[16];
  const float* head_w = (const float*)d_in[17];
  const float* head_b = (const float*)d_in[18];

  float* fp = (float*)d_ws;
  float* resid  = fp;
  float* hid    = fp + 1048576;
  float* xn     = fp + 2097152;
  float* xz     = fp + 3145728;   // T x 2048
  float* xc     = fp + 7340032;   // T x 1024
  float* dtbuf  = fp + 9437184;   // T x 1024
  float* xdb    = fp + 11534336;  // T x 32 (B|C)
  float* sP     = fp + 11665408;  // 8 x 4 x 1024 x 16
  float* sH     = fp + 12189696;
  float* part   = fp + 12713984;
  float* pooled = fp + 12746752;
  u16* us  = (u16*)(fp + 12748800);
  u16* fgb = us;                  // T x 4096
  u16* xb  = us + 8388608;        // T x 128
  u16* xnb = us + 8650752;        // T x 512
  u16* ygb = us + 9699328;        // T x 1024
  u16* mlb = us + 11796480;       // T x 2048
  u16* xcb = us + 15990784;       // T x 1024
  u16* wbh = us + 18087936;       // inp|outp|fc1|fc2|Mext(1088x1024)
  u16* wbl = us + 23920640;

  const int O_OUTP = 1048576, O_FC1 = 1572864, O_FC2 = 3670016, O_M = 4718592;

  hipMemsetAsync(resid, 0, (size_t)1048576 * 4, stream);
  k_cvt<<<256, 256, 0, stream>>>(x, xb);
  k_cvtsplit<<<64, 256, 0, stream>>>(emb_w, wbh, wbl);
  gemm_bf<2, 2><<<dim3(8, 32), 256, 0, stream>>>(xb, 128, wbh, wbl, 128, (void*)hid, 512, 128,
                                                 emb_b, nullptr, 1);

  for (int i = 0; i < 12; ++i) {
    k_wcvt<<<4608, 256, 0, stream>>>(inp_w + (size_t)i * 1048576, outp_w + (size_t)i * 524288,
                                     fc1_w + (size_t)i * 2097152, fc2_w + (size_t)i * 1048576,
                                     wbh, wbl);
    k_dtbcw<<<1088, 256, 0, stream>>>(dt_w + (size_t)i * 32768, xp_w + (size_t)i * 65536,
                                      wbh + O_M, wbl + O_M);
    k_addnorm<<<2048, 256, 0, stream>>>(resid, hid, n1_w + i * 512, xn, xnb);
    gemm_bf<4, 2><<<dim3(32, 16), 256, 0, stream>>>(xnb, 512, wbh, wbl, 512,
                                                    (void*)xz, 2048, 512, nullptr, nullptr, 0);
    k_conv<<<8192, 256, 0, stream>>>(xz, conv_w + (size_t)i * 4096, conv_b + i * 1024, xc, xcb);
    gemm_bf<4, 2><<<dim3(17, 16), 256, 0, stream>>>(xcb, 1024, wbh + O_M, wbl + O_M, 1024,
                                                    (void*)dtbuf, 1024, 1024, dt_b + i * 1024, xdb, 3);
    k_scan1<<<512, 256, 0, stream>>>(dtbuf, xc, xdb, a_log + (size_t)i * 16384, sP, sH);
    k_scan3<<<512, 256, 0, stream>>>(dtbuf, xc, xdb, a_log + (size_t)i * 16384, sP, sH,
                                     xz, Dw + i * 1024, ygb);
    gemm_bf<2, 2><<<dim3(8, 32), 256, 0, stream>>>(ygb, 1024, wbh + O_OUTP, wbl + O_OUTP, 1024,
                                                   (void*)hid, 512, 1024, nullptr, nullptr, 0);
    k_addnorm<<<2048, 256, 0, stream>>>(resid, hid, n2_w + i * 512, xn, xnb);
    gemm_bf<4, 4><<<dim3(32, 16), 256, 0, stream>>>(xnb, 512, wbh + O_FC1, wbl + O_FC1, 512,
                                                    (void*)fgb, 4096, 512, nullptr, nullptr, 2);
    k_glu_bf<<<4096, 256, 0, stream>>>(fgb, mlb);
    gemm_bf<2, 2><<<dim3(8, 32), 256, 0, stream>>>(mlb, 2048, wbh + O_FC2, wbl + O_FC2, 2048,
                                                   (void*)hid, 512, 2048, nullptr, nullptr, 0);
  }

  k_addnorm<<<2048, 256, 0, stream>>>(resid, hid, nf_w, xn, xnb);
  k_pool1<<<64, 256, 0, stream>>>(xn, part);
  k_pool2<<<8, 256, 0, stream>>>(part, pooled);
  k_head<<<200, 64, 0, stream>>>(pooled, head_w, head_b, (float*)d_out);
}

// Round 4
// 2099.864 us; speedup vs baseline: 2.3297x; 1.2113x over previous
//
#include <hip/hip_runtime.h>

typedef __attribute__((ext_vector_type(4))) float f32x4;
typedef __attribute__((ext_vector_type(8))) short s16x8;
typedef __attribute__((ext_vector_type(4))) unsigned short u16x4;
typedef unsigned short u16;

// ---------- bf16 helpers (RNE) ----------
__device__ inline u16 f2bf(float x) {
  unsigned u = __float_as_uint(x);
  return (u16)((u + 0x7fffu + ((u >> 16) & 1u)) >> 16);
}
__device__ inline float bf2f(u16 h) {
  return __uint_as_float(((unsigned)h) << 16);
}

__device__ inline void glds16(const void* g, void* l) {
  __builtin_amdgcn_global_load_lds((const __attribute__((address_space(1))) void*)g,
                                   (__attribute__((address_space(3))) void*)l, 16, 0, 0);
}

// ---------- GEMM: C[M,N] = A[M,K] (bf16) @ sum_i Wi[N,K]^T ----------
// BM=32*FM, BN=32*FN, BK=64; 4 waves (2x2); global_load_lds w16; linear LDS dest +
// source-side XOR-unit swizzle, same involution on read (<=2-way bank aliasing).
// NWB weight buffers: (W0=hi,W1=lo) split; MODE 4 adds (W2=gate_hi,W3=gate_lo).
// MODE: 0=f32 out, 1=f32+bias, 2=bf16 out, 3=dt epilogue, 4=GLU bf16 out.
template<int FM, int FN, int NWB, int MODE>
__global__ __launch_bounds__(256)
void gemm_bf(const u16* __restrict__ A, int lda,
             const u16* __restrict__ W0, const u16* __restrict__ W1,
             const u16* __restrict__ W2, const u16* __restrict__ W3, int ldw,
             void* __restrict__ Cv, int ldc, int K,
             const float* __restrict__ bias, float* __restrict__ aux) {
  constexpr int BM = 32 * FM, BN = 32 * FN, BK = 64;
  constexpr int CA = BM / 8, CW = BN / 8, TOT = CA + NWB * CW;
  __shared__ alignas(16) u16 lA[BM * BK];
  __shared__ alignas(16) u16 lW[NWB][BN * BK];
  const int tid = threadIdx.x, wave = tid >> 6, lane = tid & 63;
  const int m0 = blockIdx.y * BM, n0 = blockIdx.x * BN;
  const int wr = (wave >> 1) * (16 * FM), wc = (wave & 1) * (16 * FN);
  const int fr = lane & 15, fq = lane >> 4;
  const int rin = lane >> 3, c8 = lane & 7;
  const u16* Ws[4] = {W0, W1, W2, W3};
  f32x4 acc[FM][FN] = {};
  f32x4 acc2[FM][FN] = {};
  for (int k0 = 0; k0 < K; k0 += BK) {
    __syncthreads();
    #pragma unroll
    for (int c = 0; c < TOT; ++c) {
      if ((c & 3) != wave) continue;
      if (c < CA) {
        int row = c * 8 + rin;
        glds16(A + (size_t)(m0 + row) * lda + k0 + ((c8 ^ (row & 7)) * 8), &lA[c * 512]);
      } else {
        constexpr int CWc = CW;
        int wi = (c - CA) / CWc, ch = (c - CA) % CWc;
        int row = ch * 8 + rin;
        glds16(Ws[wi] + (size_t)(n0 + row) * ldw + k0 + ((c8 ^ (row & 7)) * 8),
               &lW[wi][ch * 512]);
      }
    }
    __syncthreads();
    #pragma unroll
    for (int s = 0; s < 2; ++s) {
      s16x8 af[FM];
      #pragma unroll
      for (int mi = 0; mi < FM; ++mi) {
        int r = wr + mi * 16 + fr;
        int u = s * 4 + fq;
        af[mi] = *reinterpret_cast<const s16x8*>(&lA[r * 64 + ((u ^ (r & 7)) * 8)]);
      }
      #pragma unroll
      for (int wi = 0; wi < NWB; ++wi) {
        #pragma unroll
        for (int ni = 0; ni < FN; ++ni) {
          int r = wc + ni * 16 + fr;
          int u = s * 4 + fq;
          s16x8 bfr = *reinterpret_cast<const s16x8*>(&lW[wi][r * 64 + ((u ^ (r & 7)) * 8)]);
          #pragma unroll
          for (int mi = 0; mi < FM; ++mi) {
            if (MODE == 4 && wi >= 2)
              acc2[mi][ni] = __builtin_amdgcn_mfma_f32_16x16x32_bf16(af[mi], bfr, acc2[mi][ni], 0, 0, 0);
            else
              acc[mi][ni] = __builtin_amdgcn_mfma_f32_16x16x32_bf16(af[mi], bfr, acc[mi][ni], 0, 0, 0);
          }
        }
      }
    }
  }
  #pragma unroll
  for (int mi = 0; mi < FM; ++mi)
    #pragma unroll
    for (int ni = 0; ni < FN; ++ni) {
      int gm = m0 + wr + mi * 16 + fq * 4;
      int gn = n0 + wc + ni * 16 + fr;
      if (MODE == 2) {
        u16* Cb = (u16*)Cv;
        #pragma unroll
        for (int r = 0; r < 4; ++r)
          Cb[(size_t)(gm + r) * ldc + gn] = f2bf(acc[mi][ni][r]);
      } else if (MODE == 4) {
        u16* Cb = (u16*)Cv;
        #pragma unroll
        for (int r = 0; r < 4; ++r) {
          float y = acc[mi][ni][r], g = acc2[mi][ni][r];
          Cb[(size_t)(gm + r) * ldc + gn] = f2bf(y * (g / (1.f + __expf(-g))));
        }
      } else if (MODE == 3) {
        float* C = (float*)Cv;
        if (gn < 1024) {
          float badd = bias[gn];
          #pragma unroll
          for (int r = 0; r < 4; ++r) {
            float s = acc[mi][ni][r] + badd;
            s = (s > 20.f) ? s : log1pf(__expf(s));
            C[(size_t)(gm + r) * ldc + gn] = s;
          }
        } else if (gn < 1056) {
          #pragma unroll
          for (int r = 0; r < 4; ++r)
            aux[(size_t)(gm + r) * 32 + (gn - 1024)] = acc[mi][ni][r];
        }
      } else {
        float* C = (float*)Cv;
        float badd = (MODE == 1) ? bias[gn] : 0.f;
        #pragma unroll
        for (int r = 0; r < 4; ++r)
          C[(size_t)(gm + r) * ldc + gn] = acc[mi][ni][r] + badd;
      }
    }
}

// ---------- weight conversion: fp32 -> bf16 hi/lo ----------
__global__ void k_wcvt(const float* __restrict__ s0, const float* __restrict__ s1,
                       const float* __restrict__ s2, const float* __restrict__ s3,
                       u16* __restrict__ wh, u16* __restrict__ wl) {
  int i4 = blockIdx.x * 256 + threadIdx.x;
  size_t idx = (size_t)i4 * 4;
  const float* s; size_t off;
  if (idx < 1048576)      { s = s0; off = idx; }
  else if (idx < 1572864) { s = s1; off = idx - 1048576; }
  else if (idx < 3670016) { s = s2; off = idx - 1572864; }
  else                    { s = s3; off = idx - 3670016; }
  f32x4 v = *reinterpret_cast<const f32x4*>(s + off);
  u16x4 hv, lv;
  #pragma unroll
  for (int j = 0; j < 4; ++j) {
    u16 hb = f2bf(v[j]);
    hv[j] = hb;
    lv[j] = f2bf(v[j] - bf2f(hb));
  }
  *reinterpret_cast<u16x4*>(wh + idx) = hv;
  *reinterpret_cast<u16x4*>(wl + idx) = lv;
}

__global__ void k_cvtsplit(const float* __restrict__ s, u16* __restrict__ wh, u16* __restrict__ wl) {
  int i4 = blockIdx.x * 256 + threadIdx.x;
  size_t idx = (size_t)i4 * 4;
  f32x4 v = *reinterpret_cast<const f32x4*>(s + idx);
  u16x4 hv, lv;
  #pragma unroll
  for (int j = 0; j < 4; ++j) {
    u16 hb = f2bf(v[j]);
    hv[j] = hb;
    lv[j] = f2bf(v[j] - bf2f(hb));
  }
  *reinterpret_cast<u16x4*>(wh + idx) = hv;
  *reinterpret_cast<u16x4*>(wl + idx) = lv;
}

__global__ void k_cvt(const float* __restrict__ s, u16* __restrict__ d) {
  int i4 = blockIdx.x * 256 + threadIdx.x;
  size_t idx = (size_t)i4 * 4;
  f32x4 v = *reinterpret_cast<const f32x4*>(s + idx);
  u16x4 o;
  #pragma unroll
  for (int j = 0; j < 4; ++j) o[j] = f2bf(v[j]);
  *reinterpret_cast<u16x4*>(d + idx) = o;
}

// ---------- dt+BC extended weight (hi/lo): rows 0..1023 = dtw@xpw_dt; 1024..1055 = xpw B,C; pad 0 ----------
__global__ void k_dtbcw(const float* __restrict__ dtw, const float* __restrict__ xpw,
                        u16* __restrict__ mh, u16* __restrict__ ml) {
  int o = blockIdx.x, tid = threadIdx.x;
  float a[4] = {};
  if (o < 1024) {
    __shared__ float lw[32];
    if (tid < 32) lw[tid] = dtw[o * 32 + tid];
    __syncthreads();
    for (int r = 0; r < 32; ++r) {
      f32x4 xv = *reinterpret_cast<const f32x4*>(xpw + (size_t)r * 1024 + tid * 4);
      float wv = lw[r];
      #pragma unroll
      for (int j = 0; j < 4; ++j) a[j] += wv * xv[j];
    }
  } else if (o < 1056) {
    f32x4 xv = *reinterpret_cast<const f32x4*>(xpw + (size_t)(o - 1024 + 32) * 1024 + tid * 4);
    #pragma unroll
    for (int j = 0; j < 4; ++j) a[j] = xv[j];
  }
  u16x4 hv, lv;
  #pragma unroll
  for (int j = 0; j < 4; ++j) {
    u16 hb = f2bf(a[j]);
    hv[j] = hb;
    lv[j] = f2bf(a[j] - bf2f(hb));
  }
  *reinterpret_cast<u16x4*>(mh + (size_t)o * 1024 + tid * 4) = hv;
  *reinterpret_cast<u16x4*>(ml + (size_t)o * 1024 + tid * 4) = lv;
}

// ---------- residual add + rmsnorm (fp32 resid, optional fp32 out, bf16 normed) ----------
__global__ void k_addnorm(float* __restrict__ r, const float* __restrict__ h,
                          const float* __restrict__ w, float* __restrict__ o,
                          u16* __restrict__ ob) {
  int t = blockIdx.x, tid = threadIdx.x;
  size_t base = (size_t)t * 512;
  float s0 = r[base + tid] + h[base + tid];
  float s1 = r[base + 256 + tid] + h[base + 256 + tid];
  float ss = s0 * s0 + s1 * s1;
  for (int m = 32; m; m >>= 1) ss += __shfl_xor(ss, m);
  __shared__ float red[4];
  if ((tid & 63) == 0) red[tid >> 6] = ss;
  __syncthreads();
  float tot = red[0] + red[1] + red[2] + red[3];
  float sc = rsqrtf(tot * (1.f / 512.f) + 1e-5f);
  r[base + tid] = s0;
  r[base + 256 + tid] = s1;
  float o0 = s0 * sc * w[tid], o1 = s1 * sc * w[tid + 256];
  if (o) {
    o[base + tid] = o0;
    o[base + 256 + tid] = o1;
  }
  ob[base + tid] = f2bf(o0);
  ob[base + 256 + tid] = f2bf(o1);
}

// ---------- causal depthwise conv (4 taps) + silu; bf16 in, fp32 + bf16 out ----------
__global__ void k_conv(const u16* __restrict__ xzb, const float* __restrict__ cw,
                       const float* __restrict__ cb, float* __restrict__ xc,
                       u16* __restrict__ xcb) {
  int idx = blockIdx.x * 256 + threadIdx.x;    // d-quad id, 524288 total
  int t = idx >> 8, q4 = (idx & 255) * 4;
  int l = t & 511;
  f32x4 w0 = *reinterpret_cast<const f32x4*>(cw + (q4 + 0) * 4);
  f32x4 w1 = *reinterpret_cast<const f32x4*>(cw + (q4 + 1) * 4);
  f32x4 w2 = *reinterpret_cast<const f32x4*>(cw + (q4 + 2) * 4);
  f32x4 w3 = *reinterpret_cast<const f32x4*>(cw + (q4 + 3) * 4);
  f32x4 a = *reinterpret_cast<const f32x4*>(cb + q4);
  #pragma unroll
  for (int j = 0; j < 4; ++j) {
    int lj = l - 3 + j;
    if (lj >= 0) {
      u16x4 v = *reinterpret_cast<const u16x4*>(xzb + (size_t)(t - 3 + j) * 2048 + q4);
      a[0] += w0[j] * bf2f(v[0]);
      a[1] += w1[j] * bf2f(v[1]);
      a[2] += w2[j] * bf2f(v[2]);
      a[3] += w3[j] * bf2f(v[3]);
    }
  }
  f32x4 so;
  u16x4 ob;
  #pragma unroll
  for (int j = 0; j < 4; ++j) {
    float s = a[j] / (1.f + __expf(-a[j]));
    so[j] = s;
    ob[j] = f2bf(s);
  }
  *reinterpret_cast<f32x4*>(xc + (size_t)t * 1024 + q4) = so;
  *reinterpret_cast<u16x4*>(xcb + (size_t)t * 1024 + q4) = ob;
}

// ---------- scan pass 1: per-chunk decay product P and local end-state H ----------
__global__ __launch_bounds__(256) void k_scan1(
    const float* __restrict__ dt, const float* __restrict__ xc,
    const float* __restrict__ xdb, const float* __restrict__ alog,
    float* __restrict__ sP, float* __restrict__ sH) {
  int bid = blockIdx.x;
  int b = bid >> 7, dg = (bid >> 3) & 15, c = bid & 7;
  int tid = threadIdx.x, dl = tid >> 2, sq = tid & 3;
  int d = dg * 64 + dl;
  int t0 = b * 512 + c * 64;
  __shared__ float ldt[16][64], lxc[16][64], lB[16][16];
  f32x4 al = *reinterpret_cast<const f32x4*>(alog + (size_t)d * 16 + sq * 4);
  float A[4], h[4] = {}, P[4] = {1.f, 1.f, 1.f, 1.f};
  #pragma unroll
  for (int j = 0; j < 4; ++j) A[j] = -__expf(al[j]);
  for (int tile = 0; tile < 4; ++tile) {
    int tt = t0 + tile * 16;
    __syncthreads();
    {
      int row = tid >> 4, f4 = (tid & 15) * 4;
      *reinterpret_cast<f32x4*>(&ldt[row][f4]) =
          *reinterpret_cast<const f32x4*>(dt + (size_t)(tt + row) * 1024 + dg * 64 + f4);
      *reinterpret_cast<f32x4*>(&lxc[row][f4]) =
          *reinterpret_cast<const f32x4*>(xc + (size_t)(tt + row) * 1024 + dg * 64 + f4);
    }
    if (tid < 64) {
      int row = tid >> 2, f4 = (tid & 3) * 4;
      *reinterpret_cast<f32x4*>(&lB[row][f4]) =
          *reinterpret_cast<const f32x4*>(xdb + (size_t)(tt + row) * 32 + f4);
    }
    __syncthreads();
    for (int lr = 0; lr < 16; ++lr) {
      float dtv = ldt[lr][dl];
      float dtx = dtv * lxc[lr][dl];
      f32x4 Bv = *reinterpret_cast<const f32x4*>(&lB[lr][sq * 4]);
      #pragma unroll
      for (int j = 0; j < 4; ++j) {
        float e = __expf(dtv * A[j]);
        h[j] = h[j] * e + dtx * Bv[j];
        P[j] *= e;
      }
    }
  }
  size_t base = ((size_t)(c * 4 + b) * 1024 + d) * 16 + sq * 4;
  *reinterpret_cast<f32x4*>(sP + base) = (f32x4){P[0], P[1], P[2], P[3]};
  *reinterpret_cast<f32x4*>(sH + base) = (f32x4){h[0], h[1], h[2], h[3]};
}

// ---------- scan pass 2: combine chunk states, replay, fuse D-skip + silu(z), bf16 out ----------
__global__ __launch_bounds__(256) void k_scan3(
    const float* __restrict__ dt, const float* __restrict__ xc,
    const float* __restrict__ xdb, const float* __restrict__ alog,
    const float* __restrict__ sP, const float* __restrict__ sH,
    const u16* __restrict__ xzb, const float* __restrict__ Dw,
    u16* __restrict__ ygb) {
  int bid = blockIdx.x;
  int b = bid >> 7, dg = (bid >> 3) & 15, c = bid & 7;
  int tid = threadIdx.x, dl = tid >> 2, sq = tid & 3;
  int d = dg * 64 + dl;
  int t0 = b * 512 + c * 64;
  __shared__ float ldt[16][64], lxc[16][64], lB[16][16], lC[16][16], ly[16][64];
  f32x4 al = *reinterpret_cast<const f32x4*>(alog + (size_t)d * 16 + sq * 4);
  float A[4], h[4] = {};
  #pragma unroll
  for (int j = 0; j < 4; ++j) A[j] = -__expf(al[j]);
  {
    size_t base = ((size_t)b * 1024 + d) * 16 + sq * 4;
    for (int cc = 0; cc < c; ++cc) {
      f32x4 Pp = *reinterpret_cast<const f32x4*>(sP + (size_t)cc * 65536 + base);
      f32x4 Hh = *reinterpret_cast<const f32x4*>(sH + (size_t)cc * 65536 + base);
      #pragma unroll
      for (int j = 0; j < 4; ++j) h[j] = Pp[j] * h[j] + Hh[j];
    }
  }
  for (int tile = 0; tile < 4; ++tile) {
    int tt = t0 + tile * 16;
    __syncthreads();
    {
      int row = tid >> 4, f4 = (tid & 15) * 4;
      *reinterpret_cast<f32x4*>(&ldt[row][f4]) =
          *reinterpret_cast<const f32x4*>(dt + (size_t)(tt + row) * 1024 + dg * 64 + f4);
      *reinterpret_cast<f32x4*>(&lxc[row][f4]) =
          *reinterpret_cast<const f32x4*>(xc + (size_t)(tt + row) * 1024 + dg * 64 + f4);
    }
    if (tid < 64) {
      int row = tid >> 2, f4 = (tid & 3) * 4;
      *reinterpret_cast<f32x4*>(&lB[row][f4]) =
          *reinterpret_cast<const f32x4*>(xdb + (size_t)(tt + row) * 32 + f4);
    } else if (tid < 128) {
      int t2 = tid - 64;
      int row = t2 >> 2, f4 = (t2 & 3) * 4;
      *reinterpret_cast<f32x4*>(&lC[row][f4]) =
          *reinterpret_cast<const f32x4*>(xdb + (size_t)(tt + row) * 32 + 16 + f4);
    }
    __syncthreads();
    for (int lr = 0; lr < 16; ++lr) {
      float dtv = ldt[lr][dl];
      float dtx = dtv * lxc[lr][dl];
      f32x4 Bv = *reinterpret_cast<const f32x4*>(&lB[lr][sq * 4]);
      f32x4 Cv = *reinterpret_cast<const f32x4*>(&lC[lr][sq * 4]);
      float py = 0.f;
      #pragma unroll
      for (int j = 0; j < 4; ++j) {
        float e = __expf(dtv * A[j]);
        h[j] = h[j] * e + dtx * Bv[j];
        py += h[j] * Cv[j];
      }
      py += __shfl_xor(py, 1);
      py += __shfl_xor(py, 2);
      if (sq == 0) ly[lr][dl] = py;
    }
    __syncthreads();
    {
      int row = tid >> 4, f4 = (tid & 15) * 4;
      f32x4 y4 = *reinterpret_cast<f32x4*>(&ly[row][f4]);
      f32x4 x4 = *reinterpret_cast<f32x4*>(&lxc[row][f4]);
      u16x4 z4 = *reinterpret_cast<const u16x4*>(xzb + (size_t)(tt + row) * 2048 + 1024 + dg * 64 + f4);
      f32x4 D4 = *reinterpret_cast<const f32x4*>(Dw + dg * 64 + f4);
      u16x4 o;
      #pragma unroll
      for (int j = 0; j < 4; ++j) {
        float yv = y4[j] + x4[j] * D4[j];
        float zz = bf2f(z4[j]);
        float g = zz / (1.f + __expf(-zz));
        o[j] = f2bf(yv * g);
      }
      *reinterpret_cast<u16x4*>(ygb + (size_t)(tt + row) * 1024 + dg * 64 + f4) = o;
    }
  }
}

// ---------- mean pool (2-stage) + head ----------
__global__ void k_pool1(const float* __restrict__ xn, float* __restrict__ part) {
  int b = blockIdx.x >> 4, lc = blockIdx.x & 15;
  int tid = threadIdx.x;
  float s0 = 0.f, s1 = 0.f;
  for (int l = lc * 32; l < lc * 32 + 32; ++l) {
    const float* row = xn + (size_t)(b * 512 + l) * 512;
    s0 += row[tid];
    s1 += row[tid + 256];
  }
  part[(size_t)blockIdx.x * 512 + tid] = s0;
  part[(size_t)blockIdx.x * 512 + tid + 256] = s1;
}

__global__ void k_pool2(const float* __restrict__ part, float* __restrict__ pooled) {
  int idx = blockIdx.x * 256 + threadIdx.x;
  int b = idx >> 9, dm = idx & 511;
  float s = 0.f;
  for (int lc = 0; lc < 16; ++lc) s += part[(size_t)(b * 16 + lc) * 512 + dm];
  pooled[idx] = s * (1.f / 512.f);
}

__global__ void k_head(const float* __restrict__ pooled, const float* __restrict__ hw,
                       const float* __restrict__ hb, float* __restrict__ out) {
  int b = blockIdx.x / 50, c = blockIdx.x % 50;
  int lane = threadIdx.x;
  float s = 0.f;
  #pragma unroll
  for (int q = 0; q < 8; ++q) {
    int dm = q * 64 + lane;
    s += pooled[b * 512 + dm] * hw[(size_t)c * 512 + dm];
  }
  for (int m = 32; m; m >>= 1) s += __shfl_xor(s, m);
  if (lane == 0) out[b * 50 + c] = s + hb[c];
}

// ---------- launch ----------
extern "C" void kernel_launch(void* const* d_in, const int* in_sizes, int n_in,
                              void* d_out, int out_size, void* d_ws, size_t ws_size,
                              hipStream_t stream) {
  (void)in_sizes; (void)n_in; (void)out_size; (void)ws_size;
  const float* x      = (const float*)d_in[0];
  const float* emb_w  = (const float*)d_in[1];
  const float* emb_b  = (const float*)d_in[2];
  const float* inp_w  = (const float*)d_in[3];
  const float* conv_w = (const float*)d_in[4];
  const float* conv_b = (const float*)d_in[5];
  const float* xp_w   = (const float*)d_in[6];
  const float* dt_w   = (const float*)d_in[7];
  const float* dt_b   = (const float*)d_in[8];
  const float* a_log  = (const float*)d_in[9];
  const float* Dw     = (const float*)d_in[10];
  const float* outp_w = (const float*)d_in[11];
  const float* n1_w   = (const float*)d_in[12];
  const float* n2_w   = (const float*)d_in[13];
  const float* fc1_w  = (const float*)d_in[14];
  const float* fc2_w  = (const float*)d_in[15];
  const float* nf_w   = (const float*)d_in[16];
  const float* head_w = (const float*)d_in[17];
  const float* head_b = (const float*)d_in[18];

  float* fp = (float*)d_ws;
  float* resid  = fp;                 // 2048 x 512
  float* hid    = fp + 1048576;
  float* xn     = fp + 2097152;
  float* xc     = fp + 3145728;       // T x 1024 fp32
  float* dtbuf  = fp + 5242880;       // T x 1024 fp32
  float* xdb    = fp + 7340032;       // T x 32
  float* sP     = fp + 7405568;       // 8 x 4 x 1024 x 16
  float* sH     = fp + 7929856;
  float* part   = fp + 8454144;
  float* pooled = fp + 8486912;
  u16* us  = (u16*)(fp + 8488960);
  u16* xzb = us;                      // T x 2048 bf16
  u16* xb  = us + 4194304;            // T x 128
  u16* xnb = us + 4456448;            // T x 512
  u16* ygb = us + 5505024;            // T x 1024
  u16* mlb = us + 7602176;            // T x 2048
  u16* xcb = us + 11796480;           // T x 1024
  u16* wbh = us + 13893632;           // inp|outp|fc1|fc2|Mext(1088x1024)
  u16* wbl = us + 19726336;

  const int O_OUTP = 1048576, O_FC1 = 1572864, O_FC2 = 3670016, O_M = 4718592;

  hipMemsetAsync(resid, 0, (size_t)1048576 * 4, stream);
  k_cvt<<<256, 256, 0, stream>>>(x, xb);
  k_cvtsplit<<<64, 256, 0, stream>>>(emb_w, wbh, wbl);
  gemm_bf<2, 1, 2, 1><<<dim3(16, 32), 256, 0, stream>>>(
      xb, 128, wbh, wbl, nullptr, nullptr, 128, (void*)hid, 512, 128, emb_b, nullptr);

  for (int i = 0; i < 12; ++i) {
    k_wcvt<<<4608, 256, 0, stream>>>(inp_w + (size_t)i * 1048576, outp_w + (size_t)i * 524288,
                                     fc1_w + (size_t)i * 2097152, fc2_w + (size_t)i * 1048576,
                                     wbh, wbl);
    k_dtbcw<<<1088, 256, 0, stream>>>(dt_w + (size_t)i * 32768, xp_w + (size_t)i * 65536,
                                      wbh + O_M, wbl + O_M);
    k_addnorm<<<2048, 256, 0, stream>>>(resid, hid, n1_w + i * 512, nullptr, xnb);
    gemm_bf<2, 2, 2, 2><<<dim3(32, 32), 256, 0, stream>>>(
        xnb, 512, wbh, wbl, nullptr, nullptr, 512, (void*)xzb, 2048, 512, nullptr, nullptr);
    k_conv<<<2048, 256, 0, stream>>>(xzb, conv_w + (size_t)i * 4096, conv_b + i * 1024, xc, xcb);
    gemm_bf<2, 2, 2, 3><<<dim3(17, 32), 256, 0, stream>>>(
        xcb, 1024, wbh + O_M, wbl + O_M, nullptr, nullptr, 1024,
        (void*)dtbuf, 1024, 1024, dt_b + i * 1024, xdb);
    k_scan1<<<512, 256, 0, stream>>>(dtbuf, xc, xdb, a_log + (size_t)i * 16384, sP, sH);
    k_scan3<<<512, 256, 0, stream>>>(dtbuf, xc, xdb, a_log + (size_t)i * 16384, sP, sH,
                                     xzb, Dw + i * 1024, ygb);
    gemm_bf<2, 1, 2, 0><<<dim3(16, 32), 256, 0, stream>>>(
        ygb, 1024, wbh + O_OUTP, wbl + O_OUTP, nullptr, nullptr, 1024,
        (void*)hid, 512, 1024, nullptr, nullptr);
    k_addnorm<<<2048, 256, 0, stream>>>(resid, hid, n2_w + i * 512, nullptr, xnb);
    gemm_bf<2, 2, 4, 4><<<dim3(32, 32), 256, 0, stream>>>(
        xnb, 512, wbh + O_FC1, wbl + O_FC1, wbh + O_FC1 + 1048576, wbl + O_FC1 + 1048576, 512,
        (void*)mlb, 2048, 512, nullptr, nullptr);
    gemm_bf<2, 1, 2, 0><<<dim3(16, 32), 256, 0, stream>>>(
        mlb, 2048, wbh + O_FC2, wbl + O_FC2, nullptr, nullptr, 2048,
        (void*)hid, 512, 2048, nullptr, nullptr);
  }

  k_addnorm<<<2048, 256, 0, stream>>>(resid, hid, nf_w, xn, xnb);
  k_pool1<<<64, 256, 0, stream>>>(xn, part);
  k_pool2<<<8, 256, 0, stream>>>(part, pooled);
  k_head<<<200, 64, 0, stream>>>(pooled, head_w, head_b, (float*)d_out);
}

// Round 6
// 1789.668 us; speedup vs baseline: 2.7335x; 1.1733x over previous
//
#include <hip/hip_runtime.h>

typedef __attribute__((ext_vector_type(4))) float f32x4;
typedef __attribute__((ext_vector_type(8))) short s16x8;
typedef __attribute__((ext_vector_type(4))) unsigned short u16x4;
typedef unsigned short u16;

// ---------- bf16 helpers (RNE) ----------
__device__ inline u16 f2bf(float x) {
  unsigned u = __float_as_uint(x);
  return (u16)((u + 0x7fffu + ((u >> 16) & 1u)) >> 16);
}
__device__ inline float bf2f(u16 h) {
  return __uint_as_float(((unsigned)h) << 16);
}

__device__ inline void glds16(const void* g, void* l) {
  __builtin_amdgcn_global_load_lds((const __attribute__((address_space(1))) void*)g,
                                   (__attribute__((address_space(3))) void*)l, 16, 0, 0);
}

// ---------- GEMM: C[M,N] = A[M,K] (bf16) @ W[N,K]^T (bf16) ----------
// BM=32*FM, BN=32*FN, BK=64; 4 waves (2x2); global_load_lds w16; linear LDS dest +
// source-side XOR swizzle, same involution on read (2-way bank aliasing = free).
// NWB=1: single weight; NWB=2 (MODE 4): W0=y-weights, W1=gate-weights (GLU).
// MODE: 0=f32 out, 1=f32+bias, 2=bf16 out, 3=dt epilogue, 4=GLU bf16 out.
template<int FM, int FN, int NWB, int MODE>
__global__ __launch_bounds__(256)
void gemm_bf(const u16* __restrict__ A, int lda,
             const u16* __restrict__ W0, const u16* __restrict__ W1, int ldw,
             void* __restrict__ Cv, int ldc, int K,
             const float* __restrict__ bias, float* __restrict__ aux) {
  constexpr int BM = 32 * FM, BN = 32 * FN, BK = 64;
  constexpr int CA = BM / 8, CW = BN / 8, TOT = CA + NWB * CW;
  __shared__ alignas(16) u16 lA[BM * BK];
  __shared__ alignas(16) u16 lW[NWB][BN * BK];
  const int tid = threadIdx.x, wave = tid >> 6, lane = tid & 63;
  const int m0 = blockIdx.y * BM, n0 = blockIdx.x * BN;
  const int wr = (wave >> 1) * (16 * FM), wc = (wave & 1) * (16 * FN);
  const int fr = lane & 15, fq = lane >> 4;
  const int rin = lane >> 3, c8 = lane & 7;
  const u16* Ws[2] = {W0, W1};
  f32x4 acc[FM][FN] = {};
  f32x4 acc2[FM][FN] = {};
  for (int k0 = 0; k0 < K; k0 += BK) {
    __syncthreads();
    #pragma unroll
    for (int c = 0; c < TOT; ++c) {
      if ((c & 3) != wave) continue;
      if (c < CA) {
        int row = c * 8 + rin;
        glds16(A + (size_t)(m0 + row) * lda + k0 + ((c8 ^ (row & 7)) * 8), &lA[c * 512]);
      } else {
        int wi = (c - CA) / CW, ch = (c - CA) % CW;
        int row = ch * 8 + rin;
        glds16(Ws[wi] + (size_t)(n0 + row) * ldw + k0 + ((c8 ^ (row & 7)) * 8),
               &lW[wi][ch * 512]);
      }
    }
    __syncthreads();
    #pragma unroll
    for (int s = 0; s < 2; ++s) {
      s16x8 af[FM];
      #pragma unroll
      for (int mi = 0; mi < FM; ++mi) {
        int r = wr + mi * 16 + fr;
        int u = s * 4 + fq;
        af[mi] = *reinterpret_cast<const s16x8*>(&lA[r * 64 + ((u ^ (r & 7)) * 8)]);
      }
      #pragma unroll
      for (int wi = 0; wi < NWB; ++wi) {
        #pragma unroll
        for (int ni = 0; ni < FN; ++ni) {
          int r = wc + ni * 16 + fr;
          int u = s * 4 + fq;
          s16x8 bfr = *reinterpret_cast<const s16x8*>(&lW[wi][r * 64 + ((u ^ (r & 7)) * 8)]);
          #pragma unroll
          for (int mi = 0; mi < FM; ++mi) {
            if (MODE == 4 && wi == 1)
              acc2[mi][ni] = __builtin_amdgcn_mfma_f32_16x16x32_bf16(af[mi], bfr, acc2[mi][ni], 0, 0, 0);
            else
              acc[mi][ni] = __builtin_amdgcn_mfma_f32_16x16x32_bf16(af[mi], bfr, acc[mi][ni], 0, 0, 0);
          }
        }
      }
    }
  }
  #pragma unroll
  for (int mi = 0; mi < FM; ++mi)
    #pragma unroll
    for (int ni = 0; ni < FN; ++ni) {
      int gm = m0 + wr + mi * 16 + fq * 4;
      int gn = n0 + wc + ni * 16 + fr;
      if (MODE == 2) {
        u16* Cb = (u16*)Cv;
        #pragma unroll
        for (int r = 0; r < 4; ++r)
          Cb[(size_t)(gm + r) * ldc + gn] = f2bf(acc[mi][ni][r]);
      } else if (MODE == 4) {
        u16* Cb = (u16*)Cv;
        #pragma unroll
        for (int r = 0; r < 4; ++r) {
          float y = acc[mi][ni][r], g = acc2[mi][ni][r];
          Cb[(size_t)(gm + r) * ldc + gn] = f2bf(y * (g / (1.f + __expf(-g))));
        }
      } else if (MODE == 3) {
        float* C = (float*)Cv;
        if (gn < 1024) {
          float badd = bias[gn];
          #pragma unroll
          for (int r = 0; r < 4; ++r) {
            float s = acc[mi][ni][r] + badd;
            s = (s > 20.f) ? s : log1pf(__expf(s));
            C[(size_t)(gm + r) * ldc + gn] = s;
          }
        } else if (gn < 1056) {
          #pragma unroll
          for (int r = 0; r < 4; ++r)
            aux[(size_t)(gm + r) * 32 + (gn - 1024)] = acc[mi][ni][r];
        }
      } else {
        float* C = (float*)Cv;
        float badd = (MODE == 1) ? bias[gn] : 0.f;
        #pragma unroll
        for (int r = 0; r < 4; ++r)
          C[(size_t)(gm + r) * ldc + gn] = acc[mi][ni][r] + badd;
      }
    }
}

// ---------- per-layer prep: weight fp32->bf16 + fused dt/BC weight ----------
// blocks [0,4608): convert inp|outp|fc1|fc2 (4,718,592 f32) to bf16
// blocks [4608,5696): row o of Mext: o<1024 dtw@xpw_dt; 1024..1055 xpw B,C; else 0
__global__ void k_prep(const float* __restrict__ inp, const float* __restrict__ outp,
                       const float* __restrict__ fc1, const float* __restrict__ fc2,
                       const float* __restrict__ dtw, const float* __restrict__ xpw,
                       u16* __restrict__ wh, u16* __restrict__ mh) {
  int blk = blockIdx.x, tid = threadIdx.x;
  if (blk < 4608) {
    size_t idx = ((size_t)blk * 256 + tid) * 4;
    const float* s; size_t off;
    if (idx < 1048576)      { s = inp;  off = idx; }
    else if (idx < 1572864) { s = outp; off = idx - 1048576; }
    else if (idx < 3670016) { s = fc1;  off = idx - 1572864; }
    else                    { s = fc2;  off = idx - 3670016; }
    f32x4 v = *reinterpret_cast<const f32x4*>(s + off);
    u16x4 hv;
    #pragma unroll
    for (int j = 0; j < 4; ++j) hv[j] = f2bf(v[j]);
    *reinterpret_cast<u16x4*>(wh + idx) = hv;
  } else {
    int o = blk - 4608;
    float a[4] = {};
    if (o < 1024) {
      __shared__ float lw[32];
      if (tid < 32) lw[tid] = dtw[o * 32 + tid];
      __syncthreads();
      for (int r = 0; r < 32; ++r) {
        f32x4 xv = *reinterpret_cast<const f32x4*>(xpw + (size_t)r * 1024 + tid * 4);
        float wv = lw[r];
        #pragma unroll
        for (int j = 0; j < 4; ++j) a[j] += wv * xv[j];
      }
    } else if (o < 1056) {
      f32x4 xv = *reinterpret_cast<const f32x4*>(xpw + (size_t)(o - 1024 + 32) * 1024 + tid * 4);
      #pragma unroll
      for (int j = 0; j < 4; ++j) a[j] = xv[j];
    }
    u16x4 hv;
    #pragma unroll
    for (int j = 0; j < 4; ++j) hv[j] = f2bf(a[j]);
    *reinterpret_cast<u16x4*>(mh + (size_t)o * 1024 + tid * 4) = hv;
  }
}

__global__ void k_cvt(const float* __restrict__ s, u16* __restrict__ d) {
  int i4 = blockIdx.x * 256 + threadIdx.x;
  size_t idx = (size_t)i4 * 4;
  f32x4 v = *reinterpret_cast<const f32x4*>(s + idx);
  u16x4 o;
  #pragma unroll
  for (int j = 0; j < 4; ++j) o[j] = f2bf(v[j]);
  *reinterpret_cast<u16x4*>(d + idx) = o;
}

// ---------- residual add + rmsnorm (fp32 resid, optional fp32 out, bf16 normed) ----------
__global__ void k_addnorm(float* __restrict__ r, const float* __restrict__ h,
                          const float* __restrict__ w, float* __restrict__ o,
                          u16* __restrict__ ob) {
  int t = blockIdx.x, tid = threadIdx.x;
  size_t base = (size_t)t * 512;
  float s0 = r[base + tid] + h[base + tid];
  float s1 = r[base + 256 + tid] + h[base + 256 + tid];
  float ss = s0 * s0 + s1 * s1;
  for (int m = 32; m; m >>= 1) ss += __shfl_xor(ss, m);
  __shared__ float red[4];
  if ((tid & 63) == 0) red[tid >> 6] = ss;
  __syncthreads();
  float tot = red[0] + red[1] + red[2] + red[3];
  float sc = rsqrtf(tot * (1.f / 512.f) + 1e-5f);
  r[base + tid] = s0;
  r[base + 256 + tid] = s1;
  float o0 = s0 * sc * w[tid], o1 = s1 * sc * w[tid + 256];
  if (o) {
    o[base + tid] = o0;
    o[base + 256 + tid] = o1;
  }
  ob[base + tid] = f2bf(o0);
  ob[base + 256 + tid] = f2bf(o1);
}

// ---------- causal depthwise conv (4 taps) + silu; bf16 in, fp32 + bf16 out ----------
__global__ void k_conv(const u16* __restrict__ xzb, const float* __restrict__ cw,
                       const float* __restrict__ cb, float* __restrict__ xc,
                       u16* __restrict__ xcb) {
  int idx = blockIdx.x * 256 + threadIdx.x;    // d-quad id
  int t = idx >> 8, q4 = (idx & 255) * 4;
  int l = t & 511;
  f32x4 w0 = *reinterpret_cast<const f32x4*>(cw + (q4 + 0) * 4);
  f32x4 w1 = *reinterpret_cast<const f32x4*>(cw + (q4 + 1) * 4);
  f32x4 w2 = *reinterpret_cast<const f32x4*>(cw + (q4 + 2) * 4);
  f32x4 w3 = *reinterpret_cast<const f32x4*>(cw + (q4 + 3) * 4);
  f32x4 a = *reinterpret_cast<const f32x4*>(cb + q4);
  #pragma unroll
  for (int j = 0; j < 4; ++j) {
    int lj = l - 3 + j;
    if (lj >= 0) {
      u16x4 v = *reinterpret_cast<const u16x4*>(xzb + (size_t)(t - 3 + j) * 2048 + q4);
      a[0] += w0[j] * bf2f(v[0]);
      a[1] += w1[j] * bf2f(v[1]);
      a[2] += w2[j] * bf2f(v[2]);
      a[3] += w3[j] * bf2f(v[3]);
    }
  }
  f32x4 so;
  u16x4 ob;
  #pragma unroll
  for (int j = 0; j < 4; ++j) {
    float s = a[j] / (1.f + __expf(-a[j]));
    so[j] = s;
    ob[j] = f2bf(s);
  }
  *reinterpret_cast<f32x4*>(xc + (size_t)t * 1024 + q4) = so;
  *reinterpret_cast<u16x4*>(xcb + (size_t)t * 1024 + q4) = ob;
}

// ---------- scan pass 1: per-chunk decay product P and local end-state H ----------
__global__ __launch_bounds__(256) void k_scan1(
    const float* __restrict__ dt, const float* __restrict__ xc,
    const float* __restrict__ xdb, const float* __restrict__ alog,
    float* __restrict__ sP, float* __restrict__ sH) {
  int bid = blockIdx.x;
  int b = bid >> 7, dg = (bid >> 3) & 15, c = bid & 7;
  int tid = threadIdx.x, dl = tid >> 2, sq = tid & 3;
  int d = dg * 64 + dl;
  int t0 = b * 512 + c * 64;
  __shared__ float ldt[16][64], lxc[16][64], lB[16][16];
  f32x4 al = *reinterpret_cast<const f32x4*>(alog + (size_t)d * 16 + sq * 4);
  float A[4], h[4] = {}, P[4] = {1.f, 1.f, 1.f, 1.f};
  #pragma unroll
  for (int j = 0; j < 4; ++j) A[j] = -__expf(al[j]);
  for (int tile = 0; tile < 4; ++tile) {
    int tt = t0 + tile * 16;
    __syncthreads();
    {
      int row = tid >> 4, f4 = (tid & 15) * 4;
      *reinterpret_cast<f32x4*>(&ldt[row][f4]) =
          *reinterpret_cast<const f32x4*>(dt + (size_t)(tt + row) * 1024 + dg * 64 + f4);
      *reinterpret_cast<f32x4*>(&lxc[row][f4]) =
          *reinterpret_cast<const f32x4*>(xc + (size_t)(tt + row) * 1024 + dg * 64 + f4);
    }
    if (tid < 64) {
      int row = tid >> 2, f4 = (tid & 3) * 4;
      *reinterpret_cast<f32x4*>(&lB[row][f4]) =
          *reinterpret_cast<const f32x4*>(xdb + (size_t)(tt + row) * 32 + f4);
    }
    __syncthreads();
    for (int lr = 0; lr < 16; ++lr) {
      float dtv = ldt[lr][dl];
      float dtx = dtv * lxc[lr][dl];
      f32x4 Bv = *reinterpret_cast<const f32x4*>(&lB[lr][sq * 4]);
      #pragma unroll
      for (int j = 0; j < 4; ++j) {
        float e = __expf(dtv * A[j]);
        h[j] = h[j] * e + dtx * Bv[j];
        P[j] *= e;
      }
    }
  }
  size_t base = ((size_t)(c * 4 + b) * 1024 + d) * 16 + sq * 4;
  *reinterpret_cast<f32x4*>(sP + base) = (f32x4){P[0], P[1], P[2], P[3]};
  *reinterpret_cast<f32x4*>(sH + base) = (f32x4){h[0], h[1], h[2], h[3]};
}

// ---------- scan pass 2: combine chunk states, replay, fuse D-skip + silu(z), bf16 out ----------
__global__ __launch_bounds__(256) void k_scan3(
    const float* __restrict__ dt, const float* __restrict__ xc,
    const float* __restrict__ xdb, const float* __restrict__ alog,
    const float* __restrict__ sP, const float* __restrict__ sH,
    const u16* __restrict__ xzb, const float* __restrict__ Dw,
    u16* __restrict__ ygb) {
  int bid = blockIdx.x;
  int b = bid >> 7, dg = (bid >> 3) & 15, c = bid & 7;
  int tid = threadIdx.x, dl = tid >> 2, sq = tid & 3;
  int d = dg * 64 + dl;
  int t0 = b * 512 + c * 64;
  __shared__ float ldt[16][64], lxc[16][64], lB[16][16], lC[16][16], ly[16][64];
  f32x4 al = *reinterpret_cast<const f32x4*>(alog + (size_t)d * 16 + sq * 4);
  float A[4], h[4] = {};
  #pragma unroll
  for (int j = 0; j < 4; ++j) A[j] = -__expf(al[j]);
  {
    size_t base = ((size_t)b * 1024 + d) * 16 + sq * 4;
    for (int cc = 0; cc < c; ++cc) {
      f32x4 Pp = *reinterpret_cast<const f32x4*>(sP + (size_t)cc * 65536 + base);
      f32x4 Hh = *reinterpret_cast<const f32x4*>(sH + (size_t)cc * 65536 + base);
      #pragma unroll
      for (int j = 0; j < 4; ++j) h[j] = Pp[j] * h[j] + Hh[j];
    }
  }
  for (int tile = 0; tile < 4; ++tile) {
    int tt = t0 + tile * 16;
    __syncthreads();
    {
      int row = tid >> 4, f4 = (tid & 15) * 4;
      *reinterpret_cast<f32x4*>(&ldt[row][f4]) =
          *reinterpret_cast<const f32x4*>(dt + (size_t)(tt + row) * 1024 + dg * 64 + f4);
      *reinterpret_cast<f32x4*>(&lxc[row][f4]) =
          *reinterpret_cast<const f32x4*>(xc + (size_t)(tt + row) * 1024 + dg * 64 + f4);
    }
    if (tid < 64) {
      int row = tid >> 2, f4 = (tid & 3) * 4;
      *reinterpret_cast<f32x4*>(&lB[row][f4]) =
          *reinterpret_cast<const f32x4*>(xdb + (size_t)(tt + row) * 32 + f4);
    } else if (tid < 128) {
      int t2 = tid - 64;
      int row = t2 >> 2, f4 = (t2 & 3) * 4;
      *reinterpret_cast<f32x4*>(&lC[row][f4]) =
          *reinterpret_cast<const f32x4*>(xdb + (size_t)(tt + row) * 32 + 16 + f4);
    }
    __syncthreads();
    for (int lr = 0; lr < 16; ++lr) {
      float dtv = ldt[lr][dl];
      float dtx = dtv * lxc[lr][dl];
      f32x4 Bv = *reinterpret_cast<const f32x4*>(&lB[lr][sq * 4]);
      f32x4 Cv = *reinterpret_cast<const f32x4*>(&lC[lr][sq * 4]);
      float py = 0.f;
      #pragma unroll
      for (int j = 0; j < 4; ++j) {
        float e = __expf(dtv * A[j]);
        h[j] = h[j] * e + dtx * Bv[j];
        py += h[j] * Cv[j];
      }
      py += __shfl_xor(py, 1);
      py += __shfl_xor(py, 2);
      if (sq == 0) ly[lr][dl] = py;
    }
    __syncthreads();
    {
      int row = tid >> 4, f4 = (tid & 15) * 4;
      f32x4 y4 = *reinterpret_cast<f32x4*>(&ly[row][f4]);
      f32x4 x4 = *reinterpret_cast<f32x4*>(&lxc[row][f4]);
      u16x4 z4 = *reinterpret_cast<const u16x4*>(xzb + (size_t)(tt + row) * 2048 + 1024 + dg * 64 + f4);
      f32x4 D4 = *reinterpret_cast<const f32x4*>(Dw + dg * 64 + f4);
      u16x4 o;
      #pragma unroll
      for (int j = 0; j < 4; ++j) {
        float yv = y4[j] + x4[j] * D4[j];
        float zz = bf2f(z4[j]);
        float g = zz / (1.f + __expf(-zz));
        o[j] = f2bf(yv * g);
      }
      *reinterpret_cast<u16x4*>(ygb + (size_t)(tt + row) * 1024 + dg * 64 + f4) = o;
    }
  }
}

// ---------- mean pool (fused 1-kernel) + head ----------
__global__ void k_pool(const float* __restrict__ xn, float* __restrict__ pooled) {
  int b = blockIdx.x >> 1, half = blockIdx.x & 1;
  int tid = threadIdx.x;
  int dm = half * 256 + tid;
  float s = 0.f;
  for (int l = 0; l < 512; ++l)
    s += xn[(size_t)(b * 512 + l) * 512 + dm];
  pooled[b * 512 + dm] = s * (1.f / 512.f);
}

__global__ void k_head(const float* __restrict__ pooled, const float* __restrict__ hw,
                       const float* __restrict__ hb, float* __restrict__ out) {
  int b = blockIdx.x / 50, c = blockIdx.x % 50;
  int lane = threadIdx.x;
  float s = 0.f;
  #pragma unroll
  for (int q = 0; q < 8; ++q) {
    int dm = q * 64 + lane;
    s += pooled[b * 512 + dm] * hw[(size_t)c * 512 + dm];
  }
  for (int m = 32; m; m >>= 1) s += __shfl_xor(s, m);
  if (lane == 0) out[b * 50 + c] = s + hb[c];
}

// ---------- launch ----------
extern "C" void kernel_launch(void* const* d_in, const int* in_sizes, int n_in,
                              void* d_out, int out_size, void* d_ws, size_t ws_size,
                              hipStream_t stream) {
  (void)in_sizes; (void)n_in; (void)out_size; (void)ws_size;
  const float* x      = (const float*)d_in[0];
  const float* emb_w  = (const float*)d_in[1];
  const float* emb_b  = (const float*)d_in[2];
  const float* inp_w  = (const float*)d_in[3];
  const float* conv_w = (const float*)d_in[4];
  const float* conv_b = (const float*)d_in[5];
  const float* xp_w   = (const float*)d_in[6];
  const float* dt_w   = (const float*)d_in[7];
  const float* dt_b   = (const float*)d_in[8];
  const float* a_log  = (const float*)d_in[9];
  const float* Dw     = (const float*)d_in[10];
  const float* outp_w = (const float*)d_in[11];
  const float* n1_w   = (const float*)d_in[12];
  const float* n2_w   = (const float*)d_in[13];
  const float* fc1_w  = (const float*)d_in[14];
  const float* fc2_w  = (const float*)d_in[15];
  const float* nf_w   = (const float*)d_in[16];
  const float* head_w = (const float*)d_in[17];
  const float* head_b = (const float*)d_in[18];

  float* fp = (float*)d_ws;
  float* resid  = fp;                 // 2048 x 512
  float* hid    = fp + 1048576;
  float* xn     = fp + 2097152;
  float* xc     = fp + 3145728;       // T x 1024 fp32
  float* dtbuf  = fp + 5242880;       // T x 1024 fp32
  float* xdb    = fp + 7340032;       // T x 32
  float* sP     = fp + 7405568;       // 8 x 4 x 1024 x 16
  float* sH     = fp + 7929856;
  float* pooled = fp + 8454144;       // 2048
  u16* us  = (u16*)(fp + 8456192);
  u16* xzb = us;                      // T x 2048 bf16
  u16* xb  = us + 4194304;            // T x 128
  u16* xnb = us + 4456448;            // T x 512
  u16* ygb = us + 5505024;            // T x 1024
  u16* mlb = us + 7602176;            // T x 2048
  u16* xcb = us + 11796480;           // T x 1024
  u16* embh = us + 13893632;          // 512 x 128
  u16* wbh = us + 13959168;           // inp|outp|fc1|fc2|Mext(1088x1024)

  const int O_OUTP = 1048576, O_FC1 = 1572864, O_FC2 = 3670016, O_M = 4718592;

  hipMemsetAsync(resid, 0, (size_t)1048576 * 4, stream);
  k_cvt<<<256, 256, 0, stream>>>(x, xb);
  k_cvt<<<64, 256, 0, stream>>>(emb_w, embh);
  gemm_bf<2, 1, 1, 1><<<dim3(16, 32), 256, 0, stream>>>(
      xb, 128, embh, nullptr, 128, (void*)hid, 512, 128, emb_b, nullptr);

  for (int i = 0; i < 12; ++i) {
    k_prep<<<5696, 256, 0, stream>>>(inp_w + (size_t)i * 1048576, outp_w + (size_t)i * 524288,
                                     fc1_w + (size_t)i * 2097152, fc2_w + (size_t)i * 1048576,
                                     dt_w + (size_t)i * 32768, xp_w + (size_t)i * 65536,
                                     wbh, wbh + O_M);
    k_addnorm<<<2048, 256, 0, stream>>>(resid, hid, n1_w + i * 512, nullptr, xnb);
    gemm_bf<2, 2, 1, 2><<<dim3(32, 32), 256, 0, stream>>>(
        xnb, 512, wbh, nullptr, 512, (void*)xzb, 2048, 512, nullptr, nullptr);
    k_conv<<<2048, 256, 0, stream>>>(xzb, conv_w + (size_t)i * 4096, conv_b + i * 1024, xc, xcb);
    gemm_bf<2, 2, 1, 3><<<dim3(17, 32), 256, 0, stream>>>(
        xcb, 1024, wbh + O_M, nullptr, 1024, (void*)dtbuf, 1024, 1024, dt_b + i * 1024, xdb);
    k_scan1<<<512, 256, 0, stream>>>(dtbuf, xc, xdb, a_log + (size_t)i * 16384, sP, sH);
    k_scan3<<<512, 256, 0, stream>>>(dtbuf, xc, xdb, a_log + (size_t)i * 16384, sP, sH,
                                     xzb, Dw + i * 1024, ygb);
    gemm_bf<2, 1, 1, 0><<<dim3(16, 32), 256, 0, stream>>>(
        ygb, 1024, wbh + O_OUTP, nullptr, 1024, (void*)hid, 512, 1024, nullptr, nullptr);
    k_addnorm<<<2048, 256, 0, stream>>>(resid, hid, n2_w + i * 512, nullptr, xnb);
    gemm_bf<2, 2, 2, 4><<<dim3(32, 32), 256, 0, stream>>>(
        xnb, 512, wbh + O_FC1, wbh + O_FC1 + 1048576, 512,
        (void*)mlb, 2048, 512, nullptr, nullptr);
    gemm_bf<2, 1, 1, 0><<<dim3(16, 32), 256, 0, stream>>>(
        mlb, 2048, wbh + O_FC2, nullptr, 2048, (void*)hid, 512, 2048, nullptr, nullptr);
  }

  k_addnorm<<<2048, 256, 0, stream>>>(resid, hid, nf_w, xn, xnb);
  k_pool<<<8, 256, 0, stream>>>(xn, pooled);
  k_head<<<200, 64, 0, stream>>>(pooled, head_w, head_b, (float*)d_out);
}

// Round 7
// 1745.676 us; speedup vs baseline: 2.8024x; 1.0252x over previous
//
#include <hip/hip_runtime.h>

typedef __attribute__((ext_vector_type(4))) float f32x4;
typedef __attribute__((ext_vector_type(8))) short s16x8;
typedef __attribute__((ext_vector_type(4))) unsigned short u16x4;
typedef unsigned short u16;

// ---------- bf16 helpers (RNE) ----------
__device__ inline u16 f2bf(float x) {
  unsigned u = __float_as_uint(x);
  return (u16)((u + 0x7fffu + ((u >> 16) & 1u)) >> 16);
}
__device__ inline float bf2f(u16 h) {
  return __uint_as_float(((unsigned)h) << 16);
}

__device__ inline void glds16(const void* g, void* l) {
  __builtin_amdgcn_global_load_lds((const __attribute__((address_space(1))) void*)g,
                                   (__attribute__((address_space(3))) void*)l, 16, 0, 0);
}

// ---------- GEMM: C[M,N] = A[M,K] (bf16) @ W[N,K]^T (bf16) ----------
// BM=32*FM, BN=32*FN, BK=128; 4 waves (2x2); global_load_lds w16; linear LDS dest +
// source-side XOR swizzle over 16 k-subchunks (key=row&15), same involution on read.
// Staging chunk = 4 rows x 16 subchunks = 512 u16 (one wave-instruction, 1KB).
// NWB=1: single weight; NWB=2 (MODE 4): W0=y-weights, W1=gate-weights (GLU).
// MODE: 0=f32 out, 1=f32+bias, 2=bf16 out, 3=dt epilogue (bf16 dt + f32 aux), 4=GLU bf16.
template<int FM, int FN, int NWB, int MODE>
__global__ __launch_bounds__(256)
void gemm_bf(const u16* __restrict__ A, int lda,
             const u16* __restrict__ W0, const u16* __restrict__ W1, int ldw,
             void* __restrict__ Cv, int ldc, int K,
             const float* __restrict__ bias, float* __restrict__ aux) {
  constexpr int BM = 32 * FM, BN = 32 * FN, BK = 128;
  constexpr int CA = BM / 4, CW = BN / 4, TOT = CA + NWB * CW;
  __shared__ alignas(16) u16 lA[BM * BK];
  __shared__ alignas(16) u16 lW[NWB][BN * BK];
  const int tid = threadIdx.x, wave = tid >> 6, lane = tid & 63;
  const int m0 = blockIdx.y * BM, n0 = blockIdx.x * BN;
  const int wr = (wave >> 1) * (16 * FM), wc = (wave & 1) * (16 * FN);
  const int fr = lane & 15, fq = lane >> 4;
  const int rin = lane >> 4, c16 = lane & 15;
  const u16* Ws[2] = {W0, W1};
  f32x4 acc[FM][FN] = {};
  f32x4 acc2[FM][FN] = {};
  for (int k0 = 0; k0 < K; k0 += BK) {
    __syncthreads();
    #pragma unroll
    for (int c = 0; c < TOT; ++c) {
      if ((c & 3) != wave) continue;
      if (c < CA) {
        int row = c * 4 + rin;
        glds16(A + (size_t)(m0 + row) * lda + k0 + ((c16 ^ (row & 15)) * 8), &lA[c * 512]);
      } else {
        int wi = (c - CA) / CW, ch = (c - CA) % CW;
        int row = ch * 4 + rin;
        glds16(Ws[wi] + (size_t)(n0 + row) * ldw + k0 + ((c16 ^ (row & 15)) * 8),
               &lW[wi][ch * 512]);
      }
    }
    __syncthreads();
    #pragma unroll
    for (int s = 0; s < 4; ++s) {
      const int u = s * 4 + fq;
      s16x8 af[FM];
      #pragma unroll
      for (int mi = 0; mi < FM; ++mi) {
        int r = wr + mi * 16 + fr;
        af[mi] = *reinterpret_cast<const s16x8*>(&lA[r * 128 + ((u ^ (r & 15)) * 8)]);
      }
      #pragma unroll
      for (int wi = 0; wi < NWB; ++wi) {
        #pragma unroll
        for (int ni = 0; ni < FN; ++ni) {
          int r = wc + ni * 16 + fr;
          s16x8 bfr = *reinterpret_cast<const s16x8*>(&lW[wi][r * 128 + ((u ^ (r & 15)) * 8)]);
          #pragma unroll
          for (int mi = 0; mi < FM; ++mi) {
            if (MODE == 4 && wi == 1)
              acc2[mi][ni] = __builtin_amdgcn_mfma_f32_16x16x32_bf16(af[mi], bfr, acc2[mi][ni], 0, 0, 0);
            else
              acc[mi][ni] = __builtin_amdgcn_mfma_f32_16x16x32_bf16(af[mi], bfr, acc[mi][ni], 0, 0, 0);
          }
        }
      }
    }
  }
  #pragma unroll
  for (int mi = 0; mi < FM; ++mi)
    #pragma unroll
    for (int ni = 0; ni < FN; ++ni) {
      int gm = m0 + wr + mi * 16 + fq * 4;
      int gn = n0 + wc + ni * 16 + fr;
      if (MODE == 2) {
        u16* Cb = (u16*)Cv;
        #pragma unroll
        for (int r = 0; r < 4; ++r)
          Cb[(size_t)(gm + r) * ldc + gn] = f2bf(acc[mi][ni][r]);
      } else if (MODE == 4) {
        u16* Cb = (u16*)Cv;
        #pragma unroll
        for (int r = 0; r < 4; ++r) {
          float y = acc[mi][ni][r], g = acc2[mi][ni][r];
          Cb[(size_t)(gm + r) * ldc + gn] = f2bf(y * (g / (1.f + __expf(-g))));
        }
      } else if (MODE == 3) {
        u16* Cb = (u16*)Cv;
        if (gn < 1024) {
          float badd = bias[gn];
          #pragma unroll
          for (int r = 0; r < 4; ++r) {
            float s = acc[mi][ni][r] + badd;
            s = (s > 20.f) ? s : log1pf(__expf(s));
            Cb[(size_t)(gm + r) * ldc + gn] = f2bf(s);
          }
        } else if (gn < 1056) {
          #pragma unroll
          for (int r = 0; r < 4; ++r)
            aux[(size_t)(gm + r) * 32 + (gn - 1024)] = acc[mi][ni][r];
        }
      } else {
        float* C = (float*)Cv;
        float badd = (MODE == 1) ? bias[gn] : 0.f;
        #pragma unroll
        for (int r = 0; r < 4; ++r)
          C[(size_t)(gm + r) * ldc + gn] = acc[mi][ni][r] + badd;
      }
    }
}

// ---------- upfront prep for ALL layers: weight fp32->bf16 + fused dt/BC weight ----------
// per layer: blocks [0,4608) convert inp|outp|fc1|fc2 (4,718,592 f32);
// blocks [4608,5696): Mext row o: o<1024 dtw@xpw_dt; 1024..1055 xpw B,C; else 0.
__global__ void k_prep(const float* __restrict__ inp_a, const float* __restrict__ outp_a,
                       const float* __restrict__ fc1_a, const float* __restrict__ fc2_a,
                       const float* __restrict__ dtw_a, const float* __restrict__ xpw_a,
                       u16* __restrict__ wall) {
  int blk = blockIdx.x, tid = threadIdx.x;
  int layer = blk / 5696, lb = blk % 5696;
  u16* wh = wall + (size_t)layer * 5832704;
  if (lb < 4608) {
    size_t idx = ((size_t)lb * 256 + tid) * 4;
    const float* s; size_t off;
    if (idx < 1048576)      { s = inp_a  + (size_t)layer * 1048576; off = idx; }
    else if (idx < 1572864) { s = outp_a + (size_t)layer * 524288;  off = idx - 1048576; }
    else if (idx < 3670016) { s = fc1_a  + (size_t)layer * 2097152; off = idx - 1572864; }
    else                    { s = fc2_a  + (size_t)layer * 1048576; off = idx - 3670016; }
    f32x4 v = *reinterpret_cast<const f32x4*>(s + off);
    u16x4 hv;
    #pragma unroll
    for (int j = 0; j < 4; ++j) hv[j] = f2bf(v[j]);
    *reinterpret_cast<u16x4*>(wh + idx) = hv;
  } else {
    int o = lb - 4608;
    const float* dtw = dtw_a + (size_t)layer * 32768;
    const float* xpw = xpw_a + (size_t)layer * 65536;
    float a[4] = {};
    if (o < 1024) {
      __shared__ float lw[32];
      if (tid < 32) lw[tid] = dtw[o * 32 + tid];
      __syncthreads();
      for (int r = 0; r < 32; ++r) {
        f32x4 xv = *reinterpret_cast<const f32x4*>(xpw + (size_t)r * 1024 + tid * 4);
        float wv = lw[r];
        #pragma unroll
        for (int j = 0; j < 4; ++j) a[j] += wv * xv[j];
      }
    } else if (o < 1056) {
      f32x4 xv = *reinterpret_cast<const f32x4*>(xpw + (size_t)(o - 1024 + 32) * 1024 + tid * 4);
      #pragma unroll
      for (int j = 0; j < 4; ++j) a[j] = xv[j];
    }
    u16x4 hv;
    #pragma unroll
    for (int j = 0; j < 4; ++j) hv[j] = f2bf(a[j]);
    *reinterpret_cast<u16x4*>(wh + 4718592 + (size_t)o * 1024 + tid * 4) = hv;
  }
}

__global__ void k_cvt(const float* __restrict__ s, u16* __restrict__ d) {
  int i4 = blockIdx.x * 256 + threadIdx.x;
  size_t idx = (size_t)i4 * 4;
  f32x4 v = *reinterpret_cast<const f32x4*>(s + idx);
  u16x4 o;
  #pragma unroll
  for (int j = 0; j < 4; ++j) o[j] = f2bf(v[j]);
  *reinterpret_cast<u16x4*>(d + idx) = o;
}

// ---------- residual add + rmsnorm (fp32 resid, optional fp32 out, bf16 normed) ----------
__global__ void k_addnorm(float* __restrict__ r, const float* __restrict__ h,
                          const float* __restrict__ w, float* __restrict__ o,
                          u16* __restrict__ ob) {
  int t = blockIdx.x, tid = threadIdx.x;
  size_t base = (size_t)t * 512;
  float s0 = r[base + tid] + h[base + tid];
  float s1 = r[base + 256 + tid] + h[base + 256 + tid];
  float ss = s0 * s0 + s1 * s1;
  for (int m = 32; m; m >>= 1) ss += __shfl_xor(ss, m);
  __shared__ float red[4];
  if ((tid & 63) == 0) red[tid >> 6] = ss;
  __syncthreads();
  float tot = red[0] + red[1] + red[2] + red[3];
  float sc = rsqrtf(tot * (1.f / 512.f) + 1e-5f);
  r[base + tid] = s0;
  r[base + 256 + tid] = s1;
  float o0 = s0 * sc * w[tid], o1 = s1 * sc * w[tid + 256];
  if (o) {
    o[base + tid] = o0;
    o[base + 256 + tid] = o1;
  }
  ob[base + tid] = f2bf(o0);
  ob[base + 256 + tid] = f2bf(o1);
}

// ---------- causal depthwise conv (4 taps) + silu; bf16 in, bf16 out ----------
__global__ void k_conv(const u16* __restrict__ xzb, const float* __restrict__ cw,
                       const float* __restrict__ cb, u16* __restrict__ xcb) {
  int idx = blockIdx.x * 256 + threadIdx.x;    // d-quad id
  int t = idx >> 8, q4 = (idx & 255) * 4;
  int l = t & 511;
  f32x4 w0 = *reinterpret_cast<const f32x4*>(cw + (q4 + 0) * 4);
  f32x4 w1 = *reinterpret_cast<const f32x4*>(cw + (q4 + 1) * 4);
  f32x4 w2 = *reinterpret_cast<const f32x4*>(cw + (q4 + 2) * 4);
  f32x4 w3 = *reinterpret_cast<const f32x4*>(cw + (q4 + 3) * 4);
  f32x4 a = *reinterpret_cast<const f32x4*>(cb + q4);
  #pragma unroll
  for (int j = 0; j < 4; ++j) {
    int lj = l - 3 + j;
    if (lj >= 0) {
      u16x4 v = *reinterpret_cast<const u16x4*>(xzb + (size_t)(t - 3 + j) * 2048 + q4);
      a[0] += w0[j] * bf2f(v[0]);
      a[1] += w1[j] * bf2f(v[1]);
      a[2] += w2[j] * bf2f(v[2]);
      a[3] += w3[j] * bf2f(v[3]);
    }
  }
  u16x4 ob;
  #pragma unroll
  for (int j = 0; j < 4; ++j)
    ob[j] = f2bf(a[j] / (1.f + __expf(-a[j])));
  *reinterpret_cast<u16x4*>(xcb + (size_t)t * 1024 + q4) = ob;
}

// ---------- scan pass 1: per-chunk decay product P and local end-state H ----------
__global__ __launch_bounds__(256) void k_scan1(
    const u16* __restrict__ dtb, const u16* __restrict__ xcb,
    const float* __restrict__ xdb, const float* __restrict__ alog,
    float* __restrict__ sP, float* __restrict__ sH) {
  int bid = blockIdx.x;
  int b = bid >> 7, dg = (bid >> 3) & 15, c = bid & 7;
  int tid = threadIdx.x, dl = tid >> 2, sq = tid & 3;
  int d = dg * 64 + dl;
  int t0 = b * 512 + c * 64;
  __shared__ u16 ldt[16][64], lxc[16][64];
  __shared__ float lB[16][16];
  f32x4 al = *reinterpret_cast<const f32x4*>(alog + (size_t)d * 16 + sq * 4);
  float A[4], h[4] = {}, P[4] = {1.f, 1.f, 1.f, 1.f};
  #pragma unroll
  for (int j = 0; j < 4; ++j) A[j] = -__expf(al[j]);
  for (int tile = 0; tile < 4; ++tile) {
    int tt = t0 + tile * 16;
    __syncthreads();
    {
      int row = tid >> 4, f4 = (tid & 15) * 4;
      *reinterpret_cast<u16x4*>(&ldt[row][f4]) =
          *reinterpret_cast<const u16x4*>(dtb + (size_t)(tt + row) * 1024 + dg * 64 + f4);
      *reinterpret_cast<u16x4*>(&lxc[row][f4]) =
          *reinterpret_cast<const u16x4*>(xcb + (size_t)(tt + row) * 1024 + dg * 64 + f4);
    }
    if (tid < 64) {
      int row = tid >> 2, f4 = (tid & 3) * 4;
      *reinterpret_cast<f32x4*>(&lB[row][f4]) =
          *reinterpret_cast<const f32x4*>(xdb + (size_t)(tt + row) * 32 + f4);
    }
    __syncthreads();
    for (int lr = 0; lr < 16; ++lr) {
      float dtv = bf2f(ldt[lr][dl]);
      float dtx = dtv * bf2f(lxc[lr][dl]);
      f32x4 Bv = *reinterpret_cast<const f32x4*>(&lB[lr][sq * 4]);
      #pragma unroll
      for (int j = 0; j < 4; ++j) {
        float e = __expf(dtv * A[j]);
        h[j] = h[j] * e + dtx * Bv[j];
        P[j] *= e;
      }
    }
  }
  size_t base = ((size_t)(c * 4 + b) * 1024 + d) * 16 + sq * 4;
  *reinterpret_cast<f32x4*>(sP + base) = (f32x4){P[0], P[1], P[2], P[3]};
  *reinterpret_cast<f32x4*>(sH + base) = (f32x4){h[0], h[1], h[2], h[3]};
}

// ---------- scan pass 2: combine chunk states, replay, fuse D-skip + silu(z), bf16 out ----------
__global__ __launch_bounds__(256) void k_scan3(
    const u16* __restrict__ dtb, const u16* __restrict__ xcb,
    const float* __restrict__ xdb, const float* __restrict__ alog,
    const float* __restrict__ sP, const float* __restrict__ sH,
    const u16* __restrict__ xzb, const float* __restrict__ Dw,
    u16* __restrict__ ygb) {
  int bid = blockIdx.x;
  int b = bid >> 7, dg = (bid >> 3) & 15, c = bid & 7;
  int tid = threadIdx.x, dl = tid >> 2, sq = tid & 3;
  int d = dg * 64 + dl;
  int t0 = b * 512 + c * 64;
  __shared__ u16 ldt[16][64], lxc[16][64];
  __shared__ float lB[16][16], lC[16][16], ly[16][64];
  f32x4 al = *reinterpret_cast<const f32x4*>(alog + (size_t)d * 16 + sq * 4);
  float A[4], h[4] = {};
  #pragma unroll
  for (int j = 0; j < 4; ++j) A[j] = -__expf(al[j]);
  {
    size_t base = ((size_t)b * 1024 + d) * 16 + sq * 4;
    for (int cc = 0; cc < c; ++cc) {
      f32x4 Pp = *reinterpret_cast<const f32x4*>(sP + (size_t)cc * 65536 + base);
      f32x4 Hh = *reinterpret_cast<const f32x4*>(sH + (size_t)cc * 65536 + base);
      #pragma unroll
      for (int j = 0; j < 4; ++j) h[j] = Pp[j] * h[j] + Hh[j];
    }
  }
  for (int tile = 0; tile < 4; ++tile) {
    int tt = t0 + tile * 16;
    __syncthreads();
    {
      int row = tid >> 4, f4 = (tid & 15) * 4;
      *reinterpret_cast<u16x4*>(&ldt[row][f4]) =
          *reinterpret_cast<const u16x4*>(dtb + (size_t)(tt + row) * 1024 + dg * 64 + f4);
      *reinterpret_cast<u16x4*>(&lxc[row][f4]) =
          *reinterpret_cast<const u16x4*>(xcb + (size_t)(tt + row) * 1024 + dg * 64 + f4);
    }
    if (tid < 64) {
      int row = tid >> 2, f4 = (tid & 3) * 4;
      *reinterpret_cast<f32x4*>(&lB[row][f4]) =
          *reinterpret_cast<const f32x4*>(xdb + (size_t)(tt + row) * 32 + f4);
    } else if (tid < 128) {
      int t2 = tid - 64;
      int row = t2 >> 2, f4 = (t2 & 3) * 4;
      *reinterpret_cast<f32x4*>(&lC[row][f4]) =
          *reinterpret_cast<const f32x4*>(xdb + (size_t)(tt + row) * 32 + 16 + f4);
    }
    __syncthreads();
    for (int lr = 0; lr < 16; ++lr) {
      float dtv = bf2f(ldt[lr][dl]);
      float dtx = dtv * bf2f(lxc[lr][dl]);
      f32x4 Bv = *reinterpret_cast<const f32x4*>(&lB[lr][sq * 4]);
      f32x4 Cv = *reinterpret_cast<const f32x4*>(&lC[lr][sq * 4]);
      float py = 0.f;
      #pragma unroll
      for (int j = 0; j < 4; ++j) {
        float e = __expf(dtv * A[j]);
        h[j] = h[j] * e + dtx * Bv[j];
        py += h[j] * Cv[j];
      }
      py += __shfl_xor(py, 1);
      py += __shfl_xor(py, 2);
      if (sq == 0) ly[lr][dl] = py;
    }
    __syncthreads();
    {
      int row = tid >> 4, f4 = (tid & 15) * 4;
      f32x4 y4 = *reinterpret_cast<f32x4*>(&ly[row][f4]);
      u16x4 x4 = *reinterpret_cast<u16x4*>(&lxc[row][f4]);
      u16x4 z4 = *reinterpret_cast<const u16x4*>(xzb + (size_t)(tt + row) * 2048 + 1024 + dg * 64 + f4);
      f32x4 D4 = *reinterpret_cast<const f32x4*>(Dw + dg * 64 + f4);
      u16x4 o;
      #pragma unroll
      for (int j = 0; j < 4; ++j) {
        float yv = y4[j] + bf2f(x4[j]) * D4[j];
        float zz = bf2f(z4[j]);
        float g = zz / (1.f + __expf(-zz));
        o[j] = f2bf(yv * g);
      }
      *reinterpret_cast<u16x4*>(ygb + (size_t)(tt + row) * 1024 + dg * 64 + f4) = o;
    }
  }
}

// ---------- mean pool + head ----------
__global__ void k_pool(const float* __restrict__ xn, float* __restrict__ pooled) {
  int b = blockIdx.x >> 1, half = blockIdx.x & 1;
  int tid = threadIdx.x;
  int dm = half * 256 + tid;
  float s = 0.f;
  for (int l = 0; l < 512; ++l)
    s += xn[(size_t)(b * 512 + l) * 512 + dm];
  pooled[b * 512 + dm] = s * (1.f / 512.f);
}

__global__ void k_head(const float* __restrict__ pooled, const float* __restrict__ hw,
                       const float* __restrict__ hb, float* __restrict__ out) {
  int b = blockIdx.x / 50, c = blockIdx.x % 50;
  int lane = threadIdx.x;
  float s = 0.f;
  #pragma unroll
  for (int q = 0; q < 8; ++q) {
    int dm = q * 64 + lane;
    s += pooled[b * 512 + dm] * hw[(size_t)c * 512 + dm];
  }
  for (int m = 32; m; m >>= 1) s += __shfl_xor(s, m);
  if (lane == 0) out[b * 50 + c] = s + hb[c];
}

// ---------- launch ----------
extern "C" void kernel_launch(void* const* d_in, const int* in_sizes, int n_in,
                              void* d_out, int out_size, void* d_ws, size_t ws_size,
                              hipStream_t stream) {
  (void)in_sizes; (void)n_in; (void)out_size; (void)ws_size;
  const float* x      = (const float*)d_in[0];
  const float* emb_w  = (const float*)d_in[1];
  const float* emb_b  = (const float*)d_in[2];
  const float* inp_w  = (const float*)d_in[3];
  const float* conv_w = (const float*)d_in[4];
  const float* conv_b = (const float*)d_in[5];
  const float* xp_w   = (const float*)d_in[6];
  const float* dt_w   = (const float*)d_in[7];
  const float* dt_b   = (const float*)d_in[8];
  const float* a_log  = (const float*)d_in[9];
  const float* Dw     = (const float*)d_in[10];
  const float* outp_w = (const float*)d_in[11];
  const float* n1_w   = (const float*)d_in[12];
  const float* n2_w   = (const float*)d_in[13];
  const float* fc1_w  = (const float*)d_in[14];
  const float* fc2_w  = (const float*)d_in[15];
  const float* nf_w   = (const float*)d_in[16];
  const float* head_w = (const float*)d_in[17];
  const float* head_b = (const float*)d_in[18];

  float* fp = (float*)d_ws;
  float* resid  = fp;                 // 2048 x 512
  float* hid    = fp + 1048576;
  float* xn     = fp + 2097152;       // final norm out (pool input)
  float* xdb    = fp + 3145728;       // T x 32 (B|C)
  float* sP     = fp + 3211264;       // 8 x 4 x 1024 x 16
  float* sH     = fp + 3735552;
  float* pooled = fp + 4259840;       // 2048
  u16* us  = (u16*)(fp + 4261888);
  u16* xzb  = us;                     // T x 2048
  u16* xb   = us + 4194304;           // T x 128
  u16* xnb  = us + 4456448;           // T x 512
  u16* ygb  = us + 5505024;           // T x 1024
  u16* mlb  = us + 7602176;           // T x 2048
  u16* xcb  = us + 11796480;          // T x 1024
  u16* dtb  = us + 13893632;          // T x 1024 (bf16 dt)
  u16* embh = us + 15990784;          // 512 x 128
  u16* wall = us + 16056320;          // 12 x (inp|outp|fc1|fc2|Mext) = 12 x 5,832,704

  const int O_OUTP = 1048576, O_FC1 = 1572864, O_FC2 = 3670016, O_M = 4718592;
  const size_t WSTRIDE = 5832704;

  hipMemsetAsync(resid, 0, (size_t)1048576 * 4, stream);
  k_cvt<<<256, 256, 0, stream>>>(x, xb);
  k_cvt<<<64, 256, 0, stream>>>(emb_w, embh);
  k_prep<<<68352, 256, 0, stream>>>(inp_w, outp_w, fc1_w, fc2_w, dt_w, xp_w, wall);
  gemm_bf<2, 1, 1, 1><<<dim3(16, 32), 256, 0, stream>>>(
      xb, 128, embh, nullptr, 128, (void*)hid, 512, 128, emb_b, nullptr);

  for (int i = 0; i < 12; ++i) {
    const u16* wL = wall + (size_t)i * WSTRIDE;
    k_addnorm<<<2048, 256, 0, stream>>>(resid, hid, n1_w + i * 512, nullptr, xnb);
    gemm_bf<2, 2, 1, 2><<<dim3(32, 32), 256, 0, stream>>>(
        xnb, 512, wL, nullptr, 512, (void*)xzb, 2048, 512, nullptr, nullptr);
    k_conv<<<2048, 256, 0, stream>>>(xzb, conv_w + (size_t)i * 4096, conv_b + i * 1024, xcb);
    gemm_bf<2, 2, 1, 3><<<dim3(17, 32), 256, 0, stream>>>(
        xcb, 1024, wL + O_M, nullptr, 1024, (void*)dtb, 1024, 1024, dt_b + i * 1024, xdb);
    k_scan1<<<512, 256, 0, stream>>>(dtb, xcb, xdb, a_log + (size_t)i * 16384, sP, sH);
    k_scan3<<<512, 256, 0, stream>>>(dtb, xcb, xdb, a_log + (size_t)i * 16384, sP, sH,
                                     xzb, Dw + i * 1024, ygb);
    gemm_bf<2, 1, 1, 0><<<dim3(16, 32), 256, 0, stream>>>(
        ygb, 1024, wL + O_OUTP, nullptr, 1024, (void*)hid, 512, 1024, nullptr, nullptr);
    k_addnorm<<<2048, 256, 0, stream>>>(resid, hid, n2_w + i * 512, nullptr, xnb);
    gemm_bf<2, 2, 2, 4><<<dim3(32, 32), 256, 0, stream>>>(
        xnb, 512, wL + O_FC1, wL + O_FC1 + 1048576, 512,
        (void*)mlb, 2048, 512, nullptr, nullptr);
    gemm_bf<2, 1, 1, 0><<<dim3(16, 32), 256, 0, stream>>>(
        mlb, 2048, wL + O_FC2, nullptr, 2048, (void*)hid, 512, 2048, nullptr, nullptr);
  }

  k_addnorm<<<2048, 256, 0, stream>>>(resid, hid, nf_w, xn, xnb);
  k_pool<<<8, 256, 0, stream>>>(xn, pooled);
  k_head<<<200, 64, 0, stream>>>(pooled, head_w, head_b, (float*)d_out);
}

// Round 8
// 1718.388 us; speedup vs baseline: 2.8469x; 1.0159x over previous
//
#include <hip/hip_runtime.h>

typedef __attribute__((ext_vector_type(4))) float f32x4;
typedef __attribute__((ext_vector_type(8))) short s16x8;
typedef __attribute__((ext_vector_type(4))) unsigned short u16x4;
typedef __attribute__((ext_vector_type(8))) unsigned short u16x8;
typedef unsigned short u16;

// ---------- bf16 helpers (RNE) ----------
__device__ inline u16 f2bf(float x) {
  unsigned u = __float_as_uint(x);
  return (u16)((u + 0x7fffu + ((u >> 16) & 1u)) >> 16);
}
__device__ inline float bf2f(u16 h) {
  return __uint_as_float(((unsigned)h) << 16);
}

__device__ inline void glds16(const void* g, void* l) {
  __builtin_amdgcn_global_load_lds((const __attribute__((address_space(1))) void*)g,
                                   (__attribute__((address_space(3))) void*)l, 16, 0, 0);
}

// ---------- GEMM: C[M,N] = A[M,K] (bf16) @ W[N,K]^T (bf16) ----------
// BM=32*FM, BN=32*FN, BK=128; 4 waves (2x2); global_load_lds w16; linear LDS dest +
// source-side XOR swizzle over 16 k-subchunks (key=row&15), same involution on read.
// MODE: 0=f32 out, 1=f32+bias, 2=bf16 out, 3=dt epilogue (bf16 dt + f32 aux), 4=GLU bf16.
template<int FM, int FN, int NWB, int MODE>
__global__ __launch_bounds__(256)
void gemm_bf(const u16* __restrict__ A, int lda,
             const u16* __restrict__ W0, const u16* __restrict__ W1, int ldw,
             void* __restrict__ Cv, int ldc, int K,
             const float* __restrict__ bias, float* __restrict__ aux) {
  constexpr int BM = 32 * FM, BN = 32 * FN, BK = 128;
  constexpr int CA = BM / 4, CW = BN / 4, TOT = CA + NWB * CW;
  __shared__ alignas(16) u16 lA[BM * BK];
  __shared__ alignas(16) u16 lW[NWB][BN * BK];
  const int tid = threadIdx.x, wave = tid >> 6, lane = tid & 63;
  const int m0 = blockIdx.y * BM, n0 = blockIdx.x * BN;
  const int wr = (wave >> 1) * (16 * FM), wc = (wave & 1) * (16 * FN);
  const int fr = lane & 15, fq = lane >> 4;
  const int rin = lane >> 4, c16 = lane & 15;
  const u16* Ws[2] = {W0, W1};
  f32x4 acc[FM][FN] = {};
  f32x4 acc2[FM][FN] = {};
  for (int k0 = 0; k0 < K; k0 += BK) {
    __syncthreads();
    #pragma unroll
    for (int c = 0; c < TOT; ++c) {
      if ((c & 3) != wave) continue;
      if (c < CA) {
        int row = c * 4 + rin;
        glds16(A + (size_t)(m0 + row) * lda + k0 + ((c16 ^ (row & 15)) * 8), &lA[c * 512]);
      } else {
        int wi = (c - CA) / CW, ch = (c - CA) % CW;
        int row = ch * 4 + rin;
        glds16(Ws[wi] + (size_t)(n0 + row) * ldw + k0 + ((c16 ^ (row & 15)) * 8),
               &lW[wi][ch * 512]);
      }
    }
    __syncthreads();
    #pragma unroll
    for (int s = 0; s < 4; ++s) {
      const int u = s * 4 + fq;
      s16x8 af[FM];
      #pragma unroll
      for (int mi = 0; mi < FM; ++mi) {
        int r = wr + mi * 16 + fr;
        af[mi] = *reinterpret_cast<const s16x8*>(&lA[r * 128 + ((u ^ (r & 15)) * 8)]);
      }
      #pragma unroll
      for (int wi = 0; wi < NWB; ++wi) {
        #pragma unroll
        for (int ni = 0; ni < FN; ++ni) {
          int r = wc + ni * 16 + fr;
          s16x8 bfr = *reinterpret_cast<const s16x8*>(&lW[wi][r * 128 + ((u ^ (r & 15)) * 8)]);
          #pragma unroll
          for (int mi = 0; mi < FM; ++mi) {
            if (MODE == 4 && wi == 1)
              acc2[mi][ni] = __builtin_amdgcn_mfma_f32_16x16x32_bf16(af[mi], bfr, acc2[mi][ni], 0, 0, 0);
            else
              acc[mi][ni] = __builtin_amdgcn_mfma_f32_16x16x32_bf16(af[mi], bfr, acc[mi][ni], 0, 0, 0);
          }
        }
      }
    }
  }
  #pragma unroll
  for (int mi = 0; mi < FM; ++mi)
    #pragma unroll
    for (int ni = 0; ni < FN; ++ni) {
      int gm = m0 + wr + mi * 16 + fq * 4;
      int gn = n0 + wc + ni * 16 + fr;
      if (MODE == 2) {
        u16* Cb = (u16*)Cv;
        #pragma unroll
        for (int r = 0; r < 4; ++r)
          Cb[(size_t)(gm + r) * ldc + gn] = f2bf(acc[mi][ni][r]);
      } else if (MODE == 4) {
        u16* Cb = (u16*)Cv;
        #pragma unroll
        for (int r = 0; r < 4; ++r) {
          float y = acc[mi][ni][r], g = acc2[mi][ni][r];
          Cb[(size_t)(gm + r) * ldc + gn] = f2bf(y * (g / (1.f + __expf(-g))));
        }
      } else if (MODE == 3) {
        u16* Cb = (u16*)Cv;
        if (gn < 1024) {
          float badd = bias[gn];
          #pragma unroll
          for (int r = 0; r < 4; ++r) {
            float s = acc[mi][ni][r] + badd;
            s = (s > 20.f) ? s : log1pf(__expf(s));
            Cb[(size_t)(gm + r) * ldc + gn] = f2bf(s);
          }
        } else if (gn < 1056) {
          #pragma unroll
          for (int r = 0; r < 4; ++r)
            aux[(size_t)(gm + r) * 32 + (gn - 1024)] = acc[mi][ni][r];
        }
      } else {
        float* C = (float*)Cv;
        float badd = (MODE == 1) ? bias[gn] : 0.f;
        #pragma unroll
        for (int r = 0; r < 4; ++r)
          C[(size_t)(gm + r) * ldc + gn] = acc[mi][ni][r] + badd;
      }
    }
}

// ---------- upfront prep: all-layer weight cvt (8 elem/thr) + Mext + x/emb cvt ----------
// blocks [0,27648): per-layer weight conversion (2304 blocks/layer, 2048 elems/block)
// blocks [27648,40704): Mext rows (1088/layer): o<1024 dtw@xpw_dt; 1024..1055 xpw B,C; else 0
// blocks [40704,40832): x -> bf16 (262144 elems)
// blocks [40832,40864): emb_w -> bf16 (65536 elems)
__global__ void k_prep(const float* __restrict__ x, const float* __restrict__ emb_w,
                       const float* __restrict__ inp_a, const float* __restrict__ outp_a,
                       const float* __restrict__ fc1_a, const float* __restrict__ fc2_a,
                       const float* __restrict__ dtw_a, const float* __restrict__ xpw_a,
                       u16* __restrict__ xb, u16* __restrict__ embh,
                       u16* __restrict__ wall) {
  int blk = blockIdx.x, tid = threadIdx.x;
  if (blk < 27648) {
    int layer = blk / 2304, lb = blk % 2304;
    u16* wh = wall + (size_t)layer * 5832704;
    size_t idx = ((size_t)lb * 256 + tid) * 8;
    const float* s; size_t off;
    if (idx < 1048576)      { s = inp_a  + (size_t)layer * 1048576; off = idx; }
    else if (idx < 1572864) { s = outp_a + (size_t)layer * 524288;  off = idx - 1048576; }
    else if (idx < 3670016) { s = fc1_a  + (size_t)layer * 2097152; off = idx - 1572864; }
    else                    { s = fc2_a  + (size_t)layer * 1048576; off = idx - 3670016; }
    f32x4 v0 = *reinterpret_cast<const f32x4*>(s + off);
    f32x4 v1 = *reinterpret_cast<const f32x4*>(s + off + 4);
    u16x8 hv;
    #pragma unroll
    for (int j = 0; j < 4; ++j) { hv[j] = f2bf(v0[j]); hv[4 + j] = f2bf(v1[j]); }
    *reinterpret_cast<u16x8*>(wh + idx) = hv;
  } else if (blk < 40704) {
    int t = blk - 27648;
    int layer = t / 1088, o = t % 1088;
    u16* mh = wall + (size_t)layer * 5832704 + 4718592;
    const float* dtw = dtw_a + (size_t)layer * 32768;
    const float* xpw = xpw_a + (size_t)layer * 65536;
    float a0[4] = {}, a1[4] = {};
    if (o < 1024) {
      __shared__ float lw[32];
      if (tid < 32) lw[tid] = dtw[o * 32 + tid];
      __syncthreads();
      #pragma unroll 4
      for (int r = 0; r < 32; r += 2) {
        f32x4 xv0 = *reinterpret_cast<const f32x4*>(xpw + (size_t)r * 1024 + tid * 4);
        f32x4 xv1 = *reinterpret_cast<const f32x4*>(xpw + (size_t)(r + 1) * 1024 + tid * 4);
        float w0 = lw[r], w1 = lw[r + 1];
        #pragma unroll
        for (int j = 0; j < 4; ++j) { a0[j] += w0 * xv0[j]; a1[j] += w1 * xv1[j]; }
      }
    } else if (o < 1056) {
      f32x4 xv = *reinterpret_cast<const f32x4*>(xpw + (size_t)(o - 1024 + 32) * 1024 + tid * 4);
      #pragma unroll
      for (int j = 0; j < 4; ++j) a0[j] = xv[j];
    }
    u16x4 hv;
    #pragma unroll
    for (int j = 0; j < 4; ++j) hv[j] = f2bf(a0[j] + a1[j]);
    *reinterpret_cast<u16x4*>(mh + (size_t)o * 1024 + tid * 4) = hv;
  } else if (blk < 40832) {
    size_t idx = ((size_t)(blk - 40704) * 256 + tid) * 8;
    f32x4 v0 = *reinterpret_cast<const f32x4*>(x + idx);
    f32x4 v1 = *reinterpret_cast<const f32x4*>(x + idx + 4);
    u16x8 hv;
    #pragma unroll
    for (int j = 0; j < 4; ++j) { hv[j] = f2bf(v0[j]); hv[4 + j] = f2bf(v1[j]); }
    *reinterpret_cast<u16x8*>(xb + idx) = hv;
  } else {
    size_t idx = ((size_t)(blk - 40832) * 256 + tid) * 8;
    f32x4 v0 = *reinterpret_cast<const f32x4*>(emb_w + idx);
    f32x4 v1 = *reinterpret_cast<const f32x4*>(emb_w + idx + 4);
    u16x8 hv;
    #pragma unroll
    for (int j = 0; j < 4; ++j) { hv[j] = f2bf(v0[j]); hv[4 + j] = f2bf(v1[j]); }
    *reinterpret_cast<u16x8*>(embh + idx) = hv;
  }
}

// ---------- residual add + rmsnorm; zr=1 treats resid as zero (layer 0) ----------
__global__ void k_addnorm(float* __restrict__ r, const float* __restrict__ h,
                          const float* __restrict__ w, u16* __restrict__ ob, int zr) {
  int t = blockIdx.x, tid = threadIdx.x;
  size_t base = (size_t)t * 512;
  float h0 = h[base + tid], h1 = h[base + 256 + tid];
  float s0 = zr ? h0 : (r[base + tid] + h0);
  float s1 = zr ? h1 : (r[base + 256 + tid] + h1);
  float ss = s0 * s0 + s1 * s1;
  for (int m = 32; m; m >>= 1) ss += __shfl_xor(ss, m);
  __shared__ float red[4];
  if ((tid & 63) == 0) red[tid >> 6] = ss;
  __syncthreads();
  float tot = red[0] + red[1] + red[2] + red[3];
  float sc = rsqrtf(tot * (1.f / 512.f) + 1e-5f);
  r[base + tid] = s0;
  r[base + 256 + tid] = s1;
  ob[base + tid] = f2bf(s0 * sc * w[tid]);
  ob[base + 256 + tid] = f2bf(s1 * sc * w[tid + 256]);
}

// ---------- causal depthwise conv (4 taps) + silu; bf16 in, bf16 out ----------
__global__ void k_conv(const u16* __restrict__ xzb, const float* __restrict__ cw,
                       const float* __restrict__ cb, u16* __restrict__ xcb) {
  int idx = blockIdx.x * 256 + threadIdx.x;
  int t = idx >> 8, q4 = (idx & 255) * 4;
  int l = t & 511;
  f32x4 w0 = *reinterpret_cast<const f32x4*>(cw + (q4 + 0) * 4);
  f32x4 w1 = *reinterpret_cast<const f32x4*>(cw + (q4 + 1) * 4);
  f32x4 w2 = *reinterpret_cast<const f32x4*>(cw + (q4 + 2) * 4);
  f32x4 w3 = *reinterpret_cast<const f32x4*>(cw + (q4 + 3) * 4);
  f32x4 a = *reinterpret_cast<const f32x4*>(cb + q4);
  #pragma unroll
  for (int j = 0; j < 4; ++j) {
    int lj = l - 3 + j;
    if (lj >= 0) {
      u16x4 v = *reinterpret_cast<const u16x4*>(xzb + (size_t)(t - 3 + j) * 2048 + q4);
      a[0] += w0[j] * bf2f(v[0]);
      a[1] += w1[j] * bf2f(v[1]);
      a[2] += w2[j] * bf2f(v[2]);
      a[3] += w3[j] * bf2f(v[3]);
    }
  }
  u16x4 ob;
  #pragma unroll
  for (int j = 0; j < 4; ++j)
    ob[j] = f2bf(a[j] / (1.f + __expf(-a[j])));
  *reinterpret_cast<u16x4*>(xcb + (size_t)t * 1024 + q4) = ob;
}

// ---------- scan pass 1 ----------
__global__ __launch_bounds__(256) void k_scan1(
    const u16* __restrict__ dtb, const u16* __restrict__ xcb,
    const float* __restrict__ xdb, const float* __restrict__ alog,
    float* __restrict__ sP, float* __restrict__ sH) {
  int bid = blockIdx.x;
  int b = bid >> 7, dg = (bid >> 3) & 15, c = bid & 7;
  int tid = threadIdx.x, dl = tid >> 2, sq = tid & 3;
  int d = dg * 64 + dl;
  int t0 = b * 512 + c * 64;
  __shared__ u16 ldt[16][64], lxc[16][64];
  __shared__ float lB[16][16];
  f32x4 al = *reinterpret_cast<const f32x4*>(alog + (size_t)d * 16 + sq * 4);
  float A[4], h[4] = {}, P[4] = {1.f, 1.f, 1.f, 1.f};
  #pragma unroll
  for (int j = 0; j < 4; ++j) A[j] = -__expf(al[j]);
  for (int tile = 0; tile < 4; ++tile) {
    int tt = t0 + tile * 16;
    __syncthreads();
    {
      int row = tid >> 4, f4 = (tid & 15) * 4;
      *reinterpret_cast<u16x4*>(&ldt[row][f4]) =
          *reinterpret_cast<const u16x4*>(dtb + (size_t)(tt + row) * 1024 + dg * 64 + f4);
      *reinterpret_cast<u16x4*>(&lxc[row][f4]) =
          *reinterpret_cast<const u16x4*>(xcb + (size_t)(tt + row) * 1024 + dg * 64 + f4);
    }
    if (tid < 64) {
      int row = tid >> 2, f4 = (tid & 3) * 4;
      *reinterpret_cast<f32x4*>(&lB[row][f4]) =
          *reinterpret_cast<const f32x4*>(xdb + (size_t)(tt + row) * 32 + f4);
    }
    __syncthreads();
    for (int lr = 0; lr < 16; ++lr) {
      float dtv = bf2f(ldt[lr][dl]);
      float dtx = dtv * bf2f(lxc[lr][dl]);
      f32x4 Bv = *reinterpret_cast<const f32x4*>(&lB[lr][sq * 4]);
      #pragma unroll
      for (int j = 0; j < 4; ++j) {
        float e = __expf(dtv * A[j]);
        h[j] = h[j] * e + dtx * Bv[j];
        P[j] *= e;
      }
    }
  }
  size_t base = ((size_t)(c * 4 + b) * 1024 + d) * 16 + sq * 4;
  *reinterpret_cast<f32x4*>(sP + base) = (f32x4){P[0], P[1], P[2], P[3]};
  *reinterpret_cast<f32x4*>(sH + base) = (f32x4){h[0], h[1], h[2], h[3]};
}

// ---------- scan pass 2 ----------
__global__ __launch_bounds__(256) void k_scan3(
    const u16* __restrict__ dtb, const u16* __restrict__ xcb,
    const float* __restrict__ xdb, const float* __restrict__ alog,
    const float* __restrict__ sP, const float* __restrict__ sH,
    const u16* __restrict__ xzb, const float* __restrict__ Dw,
    u16* __restrict__ ygb) {
  int bid = blockIdx.x;
  int b = bid >> 7, dg = (bid >> 3) & 15, c = bid & 7;
  int tid = threadIdx.x, dl = tid >> 2, sq = tid & 3;
  int d = dg * 64 + dl;
  int t0 = b * 512 + c * 64;
  __shared__ u16 ldt[16][64], lxc[16][64];
  __shared__ float lB[16][16], lC[16][16], ly[16][64];
  f32x4 al = *reinterpret_cast<const f32x4*>(alog + (size_t)d * 16 + sq * 4);
  float A[4], h[4] = {};
  #pragma unroll
  for (int j = 0; j < 4; ++j) A[j] = -__expf(al[j]);
  {
    size_t base = ((size_t)b * 1024 + d) * 16 + sq * 4;
    for (int cc = 0; cc < c; ++cc) {
      f32x4 Pp = *reinterpret_cast<const f32x4*>(sP + (size_t)cc * 65536 + base);
      f32x4 Hh = *reinterpret_cast<const f32x4*>(sH + (size_t)cc * 65536 + base);
      #pragma unroll
      for (int j = 0; j < 4; ++j) h[j] = Pp[j] * h[j] + Hh[j];
    }
  }
  for (int tile = 0; tile < 4; ++tile) {
    int tt = t0 + tile * 16;
    __syncthreads();
    {
      int row = tid >> 4, f4 = (tid & 15) * 4;
      *reinterpret_cast<u16x4*>(&ldt[row][f4]) =
          *reinterpret_cast<const u16x4*>(dtb + (size_t)(tt + row) * 1024 + dg * 64 + f4);
      *reinterpret_cast<u16x4*>(&lxc[row][f4]) =
          *reinterpret_cast<const u16x4*>(xcb + (size_t)(tt + row) * 1024 + dg * 64 + f4);
    }
    if (tid < 64) {
      int row = tid >> 2, f4 = (tid & 3) * 4;
      *reinterpret_cast<f32x4*>(&lB[row][f4]) =
          *reinterpret_cast<const f32x4*>(xdb + (size_t)(tt + row) * 32 + f4);
    } else if (tid < 128) {
      int t2 = tid - 64;
      int row = t2 >> 2, f4 = (t2 & 3) * 4;
      *reinterpret_cast<f32x4*>(&lC[row][f4]) =
          *reinterpret_cast<const f32x4*>(xdb + (size_t)(tt + row) * 32 + 16 + f4);
    }
    __syncthreads();
    for (int lr = 0; lr < 16; ++lr) {
      float dtv = bf2f(ldt[lr][dl]);
      float dtx = dtv * bf2f(lxc[lr][dl]);
      f32x4 Bv = *reinterpret_cast<const f32x4*>(&lB[lr][sq * 4]);
      f32x4 Cv = *reinterpret_cast<const f32x4*>(&lC[lr][sq * 4]);
      float py = 0.f;
      #pragma unroll
      for (int j = 0; j < 4; ++j) {
        float e = __expf(dtv * A[j]);
        h[j] = h[j] * e + dtx * Bv[j];
        py += h[j] * Cv[j];
      }
      py += __shfl_xor(py, 1);
      py += __shfl_xor(py, 2);
      if (sq == 0) ly[lr][dl] = py;
    }
    __syncthreads();
    {
      int row = tid >> 4, f4 = (tid & 15) * 4;
      f32x4 y4 = *reinterpret_cast<f32x4*>(&ly[row][f4]);
      u16x4 x4 = *reinterpret_cast<u16x4*>(&lxc[row][f4]);
      u16x4 z4 = *reinterpret_cast<const u16x4*>(xzb + (size_t)(tt + row) * 2048 + 1024 + dg * 64 + f4);
      f32x4 D4 = *reinterpret_cast<const f32x4*>(Dw + dg * 64 + f4);
      u16x4 o;
      #pragma unroll
      for (int j = 0; j < 4; ++j) {
        float yv = y4[j] + bf2f(x4[j]) * D4[j];
        float zz = bf2f(z4[j]);
        float g = zz / (1.f + __expf(-zz));
        o[j] = f2bf(yv * g);
      }
      *reinterpret_cast<u16x4*>(ygb + (size_t)(tt + row) * 1024 + dg * 64 + f4) = o;
    }
  }
}

// ---------- mean pool (bf16 in) + head ----------
__global__ void k_pool(const u16* __restrict__ xnb, float* __restrict__ pooled) {
  int b = blockIdx.x >> 1, half = blockIdx.x & 1;
  int tid = threadIdx.x;
  int dm = half * 256 + tid;
  float s = 0.f;
  for (int l = 0; l < 512; ++l)
    s += bf2f(xnb[(size_t)(b * 512 + l) * 512 + dm]);
  pooled[b * 512 + dm] = s * (1.f / 512.f);
}

__global__ void k_head(const float* __restrict__ pooled, const float* __restrict__ hw,
                       const float* __restrict__ hb, float* __restrict__ out) {
  int b = blockIdx.x / 50, c = blockIdx.x % 50;
  int lane = threadIdx.x;
  float s = 0.f;
  #pragma unroll
  for (int q = 0; q < 8; ++q) {
    int dm = q * 64 + lane;
    s += pooled[b * 512 + dm] * hw[(size_t)c * 512 + dm];
  }
  for (int m = 32; m; m >>= 1) s += __shfl_xor(s, m);
  if (lane == 0) out[b * 50 + c] = s + hb[c];
}

// ---------- launch ----------
extern "C" void kernel_launch(void* const* d_in, const int* in_sizes, int n_in,
                              void* d_out, int out_size, void* d_ws, size_t ws_size,
                              hipStream_t stream) {
  (void)in_sizes; (void)n_in; (void)out_size; (void)ws_size;
  const float* x      = (const float*)d_in[0];
  const float* emb_w  = (const float*)d_in[1];
  const float* emb_b  = (const float*)d_in[2];
  const float* inp_w  = (const float*)d_in[3];
  const float* conv_w = (const float*)d_in[4];
  const float* conv_b = (const float*)d_in[5];
  const float* xp_w   = (const float*)d_in[6];
  const float* dt_w   = (const float*)d_in[7];
  const float* dt_b   = (const float*)d_in[8];
  const float* a_log  = (const float*)d_in[9];
  const float* Dw     = (const float*)d_in[10];
  const float* outp_w = (const float*)d_in[11];
  const float* n1_w   = (const float*)d_in[12];
  const float* n2_w   = (const float*)d_in[13];
  const float* fc1_w  = (const float*)d_in[14];
  const float* fc2_w  = (const float*)d_in[15];
  const float* nf_w   = (const float*)d_in[16];
  const float* head_w = (const float*)d_in[17];
  const float* head_b = (const float*)d_in[18];

  float* fp = (float*)d_ws;
  float* resid  = fp;                 // 2048 x 512
  float* hid    = fp + 1048576;
  float* xdb    = fp + 2097152;       // T x 32 (B|C)
  float* sP     = fp + 2162688;       // 8 x 4 x 1024 x 16
  float* sH     = fp + 2686976;
  float* pooled = fp + 3211264;       // 2048
  u16* us  = (u16*)(fp + 3213312);
  u16* xzb  = us;                     // T x 2048
  u16* xb   = us + 4194304;           // 262144
  u16* xnb  = us + 4456448;           // T x 512
  u16* ygb  = us + 5505024;           // T x 1024
  u16* mlb  = us + 7602176;           // T x 2048
  u16* xcb  = us + 11796480;          // T x 1024
  u16* dtb  = us + 13893632;          // T x 1024
  u16* embh = us + 15990784;          // 512 x 128
  u16* wall = us + 16056320;          // 12 x 5,832,704

  const int O_OUTP = 1048576, O_FC1 = 1572864, O_FC2 = 3670016, O_M = 4718592;
  const size_t WSTRIDE = 5832704;

  k_prep<<<40864, 256, 0, stream>>>(x, emb_w, inp_w, outp_w, fc1_w, fc2_w, dt_w, xp_w,
                                    xb, embh, wall);
  gemm_bf<2, 1, 1, 1><<<dim3(16, 32), 256, 0, stream>>>(
      xb, 128, embh, nullptr, 128, (void*)hid, 512, 128, emb_b, nullptr);

  for (int i = 0; i < 12; ++i) {
    const u16* wL = wall + (size_t)i * WSTRIDE;
    k_addnorm<<<2048, 256, 0, stream>>>(resid, hid, n1_w + i * 512, xnb, i == 0 ? 1 : 0);
    gemm_bf<2, 2, 1, 2><<<dim3(32, 32), 256, 0, stream>>>(
        xnb, 512, wL, nullptr, 512, (void*)xzb, 2048, 512, nullptr, nullptr);
    k_conv<<<2048, 256, 0, stream>>>(xzb, conv_w + (size_t)i * 4096, conv_b + i * 1024, xcb);
    gemm_bf<2, 2, 1, 3><<<dim3(17, 32), 256, 0, stream>>>(
        xcb, 1024, wL + O_M, nullptr, 1024, (void*)dtb, 1024, 1024, dt_b + i * 1024, xdb);
    k_scan1<<<512, 256, 0, stream>>>(dtb, xcb, xdb, a_log + (size_t)i * 16384, sP, sH);
    k_scan3<<<512, 256, 0, stream>>>(dtb, xcb, xdb, a_log + (size_t)i * 16384, sP, sH,
                                     xzb, Dw + i * 1024, ygb);
    gemm_bf<2, 1, 1, 0><<<dim3(16, 32), 256, 0, stream>>>(
        ygb, 1024, wL + O_OUTP, nullptr, 1024, (void*)hid, 512, 1024, nullptr, nullptr);
    k_addnorm<<<2048, 256, 0, stream>>>(resid, hid, n2_w + i * 512, xnb, 0);
    gemm_bf<2, 2, 2, 4><<<dim3(32, 32), 256, 0, stream>>>(
        xnb, 512, wL + O_FC1, wL + O_FC1 + 1048576, 512,
        (void*)mlb, 2048, 512, nullptr, nullptr);
    gemm_bf<2, 1, 1, 0><<<dim3(16, 32), 256, 0, stream>>>(
        mlb, 2048, wL + O_FC2, nullptr, 2048, (void*)hid, 512, 2048, nullptr, nullptr);
  }

  k_addnorm<<<2048, 256, 0, stream>>>(resid, hid, nf_w, xnb, 0);
  k_pool<<<8, 256, 0, stream>>>(xnb, pooled);
  k_head<<<200, 64, 0, stream>>>(pooled, head_w, head_b, (float*)d_out);
}

// Round 9
// 1662.055 us; speedup vs baseline: 2.9434x; 1.0339x over previous
//
#include <hip/hip_runtime.h>

typedef __attribute__((ext_vector_type(4))) float f32x4;
typedef __attribute__((ext_vector_type(8))) short s16x8;
typedef __attribute__((ext_vector_type(4))) unsigned short u16x4;
typedef unsigned short u16;

// ---------- bf16 helpers (RNE) ----------
__device__ inline u16 f2bf(float x) {
  unsigned u = __float_as_uint(x);
  return (u16)((u + 0x7fffu + ((u >> 16) & 1u)) >> 16);
}
__device__ inline float bf2f(u16 h) {
  return __uint_as_float(((unsigned)h) << 16);
}

__device__ inline void glds16(const void* g, void* l) {
  __builtin_amdgcn_global_load_lds((const __attribute__((address_space(1))) void*)g,
                                   (__attribute__((address_space(3))) void*)l, 16, 0, 0);
}

// ---------- GEMM: C[M,N] = A[M,K] (bf16) @ W[N,K]^T (bf16) ----------
// BM=32*FM, BN=32*FN, BK=128; 4 waves (2x2); global_load_lds w16; linear LDS dest +
// source-side XOR swizzle over 16 k-subchunks (key=row&15), same involution on read.
// MODE: 0=f32 out, 1=f32+bias, 2=bf16 out, 3=dt epilogue (bf16 dt + f32 aux), 4=GLU bf16.
template<int FM, int FN, int NWB, int MODE>
__global__ __launch_bounds__(256)
void gemm_bf(const u16* __restrict__ A, int lda,
             const u16* __restrict__ W0, const u16* __restrict__ W1, int ldw,
             void* __restrict__ Cv, int ldc, int K,
             const float* __restrict__ bias, float* __restrict__ aux) {
  constexpr int BM = 32 * FM, BN = 32 * FN, BK = 128;
  constexpr int CA = BM / 4, CW = BN / 4, TOT = CA + NWB * CW;
  __shared__ alignas(16) u16 lA[BM * BK];
  __shared__ alignas(16) u16 lW[NWB][BN * BK];
  const int tid = threadIdx.x, wave = tid >> 6, lane = tid & 63;
  const int m0 = blockIdx.y * BM, n0 = blockIdx.x * BN;
  const int wr = (wave >> 1) * (16 * FM), wc = (wave & 1) * (16 * FN);
  const int fr = lane & 15, fq = lane >> 4;
  const int rin = lane >> 4, c16 = lane & 15;
  const u16* Ws[2] = {W0, W1};
  f32x4 acc[FM][FN] = {};
  f32x4 acc2[FM][FN] = {};
  for (int k0 = 0; k0 < K; k0 += BK) {
    __syncthreads();
    #pragma unroll
    for (int c = 0; c < TOT; ++c) {
      if ((c & 3) != wave) continue;
      if (c < CA) {
        int row = c * 4 + rin;
        glds16(A + (size_t)(m0 + row) * lda + k0 + ((c16 ^ (row & 15)) * 8), &lA[c * 512]);
      } else {
        int wi = (c - CA) / CW, ch = (c - CA) % CW;
        int row = ch * 4 + rin;
        glds16(Ws[wi] + (size_t)(n0 + row) * ldw + k0 + ((c16 ^ (row & 15)) * 8),
               &lW[wi][ch * 512]);
      }
    }
    __syncthreads();
    #pragma unroll
    for (int s = 0; s < 4; ++s) {
      const int u = s * 4 + fq;
      s16x8 af[FM];
      #pragma unroll
      for (int mi = 0; mi < FM; ++mi) {
        int r = wr + mi * 16 + fr;
        af[mi] = *reinterpret_cast<const s16x8*>(&lA[r * 128 + ((u ^ (r & 15)) * 8)]);
      }
      #pragma unroll
      for (int wi = 0; wi < NWB; ++wi) {
        #pragma unroll
        for (int ni = 0; ni < FN; ++ni) {
          int r = wc + ni * 16 + fr;
          s16x8 bfr = *reinterpret_cast<const s16x8*>(&lW[wi][r * 128 + ((u ^ (r & 15)) * 8)]);
          #pragma unroll
          for (int mi = 0; mi < FM; ++mi) {
            if (MODE == 4 && wi == 1)
              acc2[mi][ni] = __builtin_amdgcn_mfma_f32_16x16x32_bf16(af[mi], bfr, acc2[mi][ni], 0, 0, 0);
            else
              acc[mi][ni] = __builtin_amdgcn_mfma_f32_16x16x32_bf16(af[mi], bfr, acc[mi][ni], 0, 0, 0);
          }
        }
      }
    }
  }
  #pragma unroll
  for (int mi = 0; mi < FM; ++mi)
    #pragma unroll
    for (int ni = 0; ni < FN; ++ni) {
      int gm = m0 + wr + mi * 16 + fq * 4;
      int gn = n0 + wc + ni * 16 + fr;
      if (MODE == 2) {
        u16* Cb = (u16*)Cv;
        #pragma unroll
        for (int r = 0; r < 4; ++r)
          Cb[(size_t)(gm + r) * ldc + gn] = f2bf(acc[mi][ni][r]);
      } else if (MODE == 4) {
        u16* Cb = (u16*)Cv;
        #pragma unroll
        for (int r = 0; r < 4; ++r) {
          float y = acc[mi][ni][r], g = acc2[mi][ni][r];
          Cb[(size_t)(gm + r) * ldc + gn] = f2bf(y * (g / (1.f + __expf(-g))));
        }
      } else if (MODE == 3) {
        u16* Cb = (u16*)Cv;
        if (gn < 1024) {
          float badd = bias[gn];
          #pragma unroll
          for (int r = 0; r < 4; ++r) {
            float s = acc[mi][ni][r] + badd;
            s = (s > 20.f) ? s : log1pf(__expf(s));
            Cb[(size_t)(gm + r) * ldc + gn] = f2bf(s);
          }
        } else if (gn < 1056) {
          #pragma unroll
          for (int r = 0; r < 4; ++r)
            aux[(size_t)(gm + r) * 32 + (gn - 1024)] = acc[mi][ni][r];
        }
      } else {
        float* C = (float*)Cv;
        float badd = (MODE == 1) ? bias[gn] : 0.f;
        #pragma unroll
        for (int r = 0; r < 4; ++r)
          C[(size_t)(gm + r) * ldc + gn] = acc[mi][ni][r] + badd;
      }
    }
}

// ---------- upfront prep (fully coalesced) ----------
// blocks [0,27648): weight cvt, 2048 elems/block: per thread TWO wave-contiguous
//   f32x4 loads (tid*4, tid*4+1024) -> two u16x4 stores. 2304 blocks/layer.
// blocks [27648,29280): Mext, 136/layer: lb<128 -> 8 dt-rows/block (dtw@xpw_dt);
//   lb in [128,136) -> rows 1024..1087 (BC copy rows <1056, zero pad above).
// blocks [29280,29408): x -> bf16.  blocks [29408,29440): emb_w -> bf16.
__global__ void k_prep(const float* __restrict__ x, const float* __restrict__ emb_w,
                       const float* __restrict__ inp_a, const float* __restrict__ outp_a,
                       const float* __restrict__ fc1_a, const float* __restrict__ fc2_a,
                       const float* __restrict__ dtw_a, const float* __restrict__ xpw_a,
                       u16* __restrict__ xb, u16* __restrict__ embh,
                       u16* __restrict__ wall) {
  int blk = blockIdx.x, tid = threadIdx.x;
  if (blk < 27648) {
    int layer = blk / 2304, lb = blk % 2304;
    u16* wh = wall + (size_t)layer * 5832704;
    size_t base = (size_t)lb * 2048;
    const float* s; size_t off;
    if (base < 1048576)      { s = inp_a  + (size_t)layer * 1048576; off = base; }
    else if (base < 1572864) { s = outp_a + (size_t)layer * 524288;  off = base - 1048576; }
    else if (base < 3670016) { s = fc1_a  + (size_t)layer * 2097152; off = base - 1572864; }
    else                     { s = fc2_a  + (size_t)layer * 1048576; off = base - 3670016; }
    f32x4 v0 = *reinterpret_cast<const f32x4*>(s + off + tid * 4);
    f32x4 v1 = *reinterpret_cast<const f32x4*>(s + off + 1024 + tid * 4);
    u16x4 h0, h1;
    #pragma unroll
    for (int j = 0; j < 4; ++j) { h0[j] = f2bf(v0[j]); h1[j] = f2bf(v1[j]); }
    *reinterpret_cast<u16x4*>(wh + base + tid * 4) = h0;
    *reinterpret_cast<u16x4*>(wh + base + 1024 + tid * 4) = h1;
  } else if (blk < 29280) {
    int t = blk - 27648;
    int layer = t / 136, lb = t % 136;
    u16* mh = wall + (size_t)layer * 5832704 + 4718592;
    const float* xpw = xpw_a + (size_t)layer * 65536;
    if (lb < 128) {
      const float* dtw = dtw_a + (size_t)layer * 32768;
      int o0 = lb * 8;
      __shared__ float lw[8][32];
      if (tid < 256) {
        int row = tid >> 5, r = tid & 31;
        lw[row][r] = dtw[(o0 + row) * 32 + r];
      }
      __syncthreads();
      f32x4 a[8] = {};
      for (int r = 0; r < 32; ++r) {
        f32x4 xv = *reinterpret_cast<const f32x4*>(xpw + (size_t)r * 1024 + tid * 4);
        #pragma unroll
        for (int row = 0; row < 8; ++row) {
          float wv = lw[row][r];
          #pragma unroll
          for (int j = 0; j < 4; ++j) a[row][j] += wv * xv[j];
        }
      }
      #pragma unroll
      for (int row = 0; row < 8; ++row) {
        u16x4 hv;
        #pragma unroll
        for (int j = 0; j < 4; ++j) hv[j] = f2bf(a[row][j]);
        *reinterpret_cast<u16x4*>(mh + (size_t)(o0 + row) * 1024 + tid * 4) = hv;
      }
    } else {
      int o0 = 1024 + (lb - 128) * 8;
      #pragma unroll
      for (int row = 0; row < 8; ++row) {
        int o = o0 + row;
        u16x4 hv = {0, 0, 0, 0};
        if (o < 1056) {
          f32x4 xv = *reinterpret_cast<const f32x4*>(xpw + (size_t)(o - 1024 + 32) * 1024 + tid * 4);
          #pragma unroll
          for (int j = 0; j < 4; ++j) hv[j] = f2bf(xv[j]);
        }
        *reinterpret_cast<u16x4*>(mh + (size_t)o * 1024 + tid * 4) = hv;
      }
    }
  } else if (blk < 29408) {
    size_t base = (size_t)(blk - 29280) * 2048;
    f32x4 v0 = *reinterpret_cast<const f32x4*>(x + base + tid * 4);
    f32x4 v1 = *reinterpret_cast<const f32x4*>(x + base + 1024 + tid * 4);
    u16x4 h0, h1;
    #pragma unroll
    for (int j = 0; j < 4; ++j) { h0[j] = f2bf(v0[j]); h1[j] = f2bf(v1[j]); }
    *reinterpret_cast<u16x4*>(xb + base + tid * 4) = h0;
    *reinterpret_cast<u16x4*>(xb + base + 1024 + tid * 4) = h1;
  } else {
    size_t base = (size_t)(blk - 29408) * 2048;
    f32x4 v0 = *reinterpret_cast<const f32x4*>(emb_w + base + tid * 4);
    f32x4 v1 = *reinterpret_cast<const f32x4*>(emb_w + base + 1024 + tid * 4);
    u16x4 h0, h1;
    #pragma unroll
    for (int j = 0; j < 4; ++j) { h0[j] = f2bf(v0[j]); h1[j] = f2bf(v1[j]); }
    *reinterpret_cast<u16x4*>(embh + base + tid * 4) = h0;
    *reinterpret_cast<u16x4*>(embh + base + 1024 + tid * 4) = h1;
  }
}

// ---------- residual add + rmsnorm; zr=1 treats resid as zero (layer 0) ----------
__global__ void k_addnorm(float* __restrict__ r, const float* __restrict__ h,
                          const float* __restrict__ w, u16* __restrict__ ob, int zr) {
  int t = blockIdx.x, tid = threadIdx.x;
  size_t base = (size_t)t * 512;
  float h0 = h[base + tid], h1 = h[base + 256 + tid];
  float s0 = zr ? h0 : (r[base + tid] + h0);
  float s1 = zr ? h1 : (r[base + 256 + tid] + h1);
  float ss = s0 * s0 + s1 * s1;
  for (int m = 32; m; m >>= 1) ss += __shfl_xor(ss, m);
  __shared__ float red[4];
  if ((tid & 63) == 0) red[tid >> 6] = ss;
  __syncthreads();
  float tot = red[0] + red[1] + red[2] + red[3];
  float sc = rsqrtf(tot * (1.f / 512.f) + 1e-5f);
  r[base + tid] = s0;
  r[base + 256 + tid] = s1;
  ob[base + tid] = f2bf(s0 * sc * w[tid]);
  ob[base + 256 + tid] = f2bf(s1 * sc * w[tid + 256]);
}

// ---------- causal depthwise conv (4 taps) + silu; bf16 in, bf16 out ----------
__global__ void k_conv(const u16* __restrict__ xzb, const float* __restrict__ cw,
                       const float* __restrict__ cb, u16* __restrict__ xcb) {
  int idx = blockIdx.x * 256 + threadIdx.x;
  int t = idx >> 8, q4 = (idx & 255) * 4;
  int l = t & 511;
  f32x4 w0 = *reinterpret_cast<const f32x4*>(cw + (q4 + 0) * 4);
  f32x4 w1 = *reinterpret_cast<const f32x4*>(cw + (q4 + 1) * 4);
  f32x4 w2 = *reinterpret_cast<const f32x4*>(cw + (q4 + 2) * 4);
  f32x4 w3 = *reinterpret_cast<const f32x4*>(cw + (q4 + 3) * 4);
  f32x4 a = *reinterpret_cast<const f32x4*>(cb + q4);
  #pragma unroll
  for (int j = 0; j < 4; ++j) {
    int lj = l - 3 + j;
    if (lj >= 0) {
      u16x4 v = *reinterpret_cast<const u16x4*>(xzb + (size_t)(t - 3 + j) * 2048 + q4);
      a[0] += w0[j] * bf2f(v[0]);
      a[1] += w1[j] * bf2f(v[1]);
      a[2] += w2[j] * bf2f(v[2]);
      a[3] += w3[j] * bf2f(v[3]);
    }
  }
  u16x4 ob;
  #pragma unroll
  for (int j = 0; j < 4; ++j)
    ob[j] = f2bf(a[j] / (1.f + __expf(-a[j])));
  *reinterpret_cast<u16x4*>(xcb + (size_t)t * 1024 + q4) = ob;
}

// ---------- scan pass 1 ----------
__global__ __launch_bounds__(256) void k_scan1(
    const u16* __restrict__ dtb, const u16* __restrict__ xcb,
    const float* __restrict__ xdb, const float* __restrict__ alog,
    float* __restrict__ sP, float* __restrict__ sH) {
  int bid = blockIdx.x;
  int b = bid >> 7, dg = (bid >> 3) & 15, c = bid & 7;
  int tid = threadIdx.x, dl = tid >> 2, sq = tid & 3;
  int d = dg * 64 + dl;
  int t0 = b * 512 + c * 64;
  __shared__ u16 ldt[16][64], lxc[16][64];
  __shared__ float lB[16][16];
  f32x4 al = *reinterpret_cast<const f32x4*>(alog + (size_t)d * 16 + sq * 4);
  float A[4], h[4] = {}, P[4] = {1.f, 1.f, 1.f, 1.f};
  #pragma unroll
  for (int j = 0; j < 4; ++j) A[j] = -__expf(al[j]);
  for (int tile = 0; tile < 4; ++tile) {
    int tt = t0 + tile * 16;
    __syncthreads();
    {
      int row = tid >> 4, f4 = (tid & 15) * 4;
      *reinterpret_cast<u16x4*>(&ldt[row][f4]) =
          *reinterpret_cast<const u16x4*>(dtb + (size_t)(tt + row) * 1024 + dg * 64 + f4);
      *reinterpret_cast<u16x4*>(&lxc[row][f4]) =
          *reinterpret_cast<const u16x4*>(xcb + (size_t)(tt + row) * 1024 + dg * 64 + f4);
    }
    if (tid < 64) {
      int row = tid >> 2, f4 = (tid & 3) * 4;
      *reinterpret_cast<f32x4*>(&lB[row][f4]) =
          *reinterpret_cast<const f32x4*>(xdb + (size_t)(tt + row) * 32 + f4);
    }
    __syncthreads();
    for (int lr = 0; lr < 16; ++lr) {
      float dtv = bf2f(ldt[lr][dl]);
      float dtx = dtv * bf2f(lxc[lr][dl]);
      f32x4 Bv = *reinterpret_cast<const f32x4*>(&lB[lr][sq * 4]);
      #pragma unroll
      for (int j = 0; j < 4; ++j) {
        float e = __expf(dtv * A[j]);
        h[j] = h[j] * e + dtx * Bv[j];
        P[j] *= e;
      }
    }
  }
  size_t base = ((size_t)(c * 4 + b) * 1024 + d) * 16 + sq * 4;
  *reinterpret_cast<f32x4*>(sP + base) = (f32x4){P[0], P[1], P[2], P[3]};
  *reinterpret_cast<f32x4*>(sH + base) = (f32x4){h[0], h[1], h[2], h[3]};
}

// ---------- scan pass 2 ----------
__global__ __launch_bounds__(256) void k_scan3(
    const u16* __restrict__ dtb, const u16* __restrict__ xcb,
    const float* __restrict__ xdb, const float* __restrict__ alog,
    const float* __restrict__ sP, const float* __restrict__ sH,
    const u16* __restrict__ xzb, const float* __restrict__ Dw,
    u16* __restrict__ ygb) {
  int bid = blockIdx.x;
  int b = bid >> 7, dg = (bid >> 3) & 15, c = bid & 7;
  int tid = threadIdx.x, dl = tid >> 2, sq = tid & 3;
  int d = dg * 64 + dl;
  int t0 = b * 512 + c * 64;
  __shared__ u16 ldt[16][64], lxc[16][64];
  __shared__ float lB[16][16], lC[16][16], ly[16][64];
  f32x4 al = *reinterpret_cast<const f32x4*>(alog + (size_t)d * 16 + sq * 4);
  float A[4], h[4] = {};
  #pragma unroll
  for (int j = 0; j < 4; ++j) A[j] = -__expf(al[j]);
  {
    size_t base = ((size_t)b * 1024 + d) * 16 + sq * 4;
    for (int cc = 0; cc < c; ++cc) {
      f32x4 Pp = *reinterpret_cast<const f32x4*>(sP + (size_t)cc * 65536 + base);
      f32x4 Hh = *reinterpret_cast<const f32x4*>(sH + (size_t)cc * 65536 + base);
      #pragma unroll
      for (int j = 0; j < 4; ++j) h[j] = Pp[j] * h[j] + Hh[j];
    }
  }
  for (int tile = 0; tile < 4; ++tile) {
    int tt = t0 + tile * 16;
    __syncthreads();
    {
      int row = tid >> 4, f4 = (tid & 15) * 4;
      *reinterpret_cast<u16x4*>(&ldt[row][f4]) =
          *reinterpret_cast<const u16x4*>(dtb + (size_t)(tt + row) * 1024 + dg * 64 + f4);
      *reinterpret_cast<u16x4*>(&lxc[row][f4]) =
          *reinterpret_cast<const u16x4*>(xcb + (size_t)(tt + row) * 1024 + dg * 64 + f4);
    }
    if (tid < 64) {
      int row = tid >> 2, f4 = (tid & 3) * 4;
      *reinterpret_cast<f32x4*>(&lB[row][f4]) =
          *reinterpret_cast<const f32x4*>(xdb + (size_t)(tt + row) * 32 + f4);
    } else if (tid < 128) {
      int t2 = tid - 64;
      int row = t2 >> 2, f4 = (t2 & 3) * 4;
      *reinterpret_cast<f32x4*>(&lC[row][f4]) =
          *reinterpret_cast<const f32x4*>(xdb + (size_t)(tt + row) * 32 + 16 + f4);
    }
    __syncthreads();
    for (int lr = 0; lr < 16; ++lr) {
      float dtv = bf2f(ldt[lr][dl]);
      float dtx = dtv * bf2f(lxc[lr][dl]);
      f32x4 Bv = *reinterpret_cast<const f32x4*>(&lB[lr][sq * 4]);
      f32x4 Cv = *reinterpret_cast<const f32x4*>(&lC[lr][sq * 4]);
      float py = 0.f;
      #pragma unroll
      for (int j = 0; j < 4; ++j) {
        float e = __expf(dtv * A[j]);
        h[j] = h[j] * e + dtx * Bv[j];
        py += h[j] * Cv[j];
      }
      py += __shfl_xor(py, 1);
      py += __shfl_xor(py, 2);
      if (sq == 0) ly[lr][dl] = py;
    }
    __syncthreads();
    {
      int row = tid >> 4, f4 = (tid & 15) * 4;
      f32x4 y4 = *reinterpret_cast<f32x4*>(&ly[row][f4]);
      u16x4 x4 = *reinterpret_cast<u16x4*>(&lxc[row][f4]);
      u16x4 z4 = *reinterpret_cast<const u16x4*>(xzb + (size_t)(tt + row) * 2048 + 1024 + dg * 64 + f4);
      f32x4 D4 = *reinterpret_cast<const f32x4*>(Dw + dg * 64 + f4);
      u16x4 o;
      #pragma unroll
      for (int j = 0; j < 4; ++j) {
        float yv = y4[j] + bf2f(x4[j]) * D4[j];
        float zz = bf2f(z4[j]);
        float g = zz / (1.f + __expf(-zz));
        o[j] = f2bf(yv * g);
      }
      *reinterpret_cast<u16x4*>(ygb + (size_t)(tt + row) * 1024 + dg * 64 + f4) = o;
    }
  }
}

// ---------- mean pool (bf16 in) + head ----------
__global__ void k_pool(const u16* __restrict__ xnb, float* __restrict__ pooled) {
  int b = blockIdx.x >> 1, half = blockIdx.x & 1;
  int tid = threadIdx.x;
  int dm = half * 256 + tid;
  float s = 0.f;
  for (int l = 0; l < 512; ++l)
    s += bf2f(xnb[(size_t)(b * 512 + l) * 512 + dm]);
  pooled[b * 512 + dm] = s * (1.f / 512.f);
}

__global__ void k_head(const float* __restrict__ pooled, const float* __restrict__ hw,
                       const float* __restrict__ hb, float* __restrict__ out) {
  int b = blockIdx.x / 50, c = blockIdx.x % 50;
  int lane = threadIdx.x;
  float s = 0.f;
  #pragma unroll
  for (int q = 0; q < 8; ++q) {
    int dm = q * 64 + lane;
    s += pooled[b * 512 + dm] * hw[(size_t)c * 512 + dm];
  }
  for (int m = 32; m; m >>= 1) s += __shfl_xor(s, m);
  if (lane == 0) out[b * 50 + c] = s + hb[c];
}

// ---------- launch ----------
extern "C" void kernel_launch(void* const* d_in, const int* in_sizes, int n_in,
                              void* d_out, int out_size, void* d_ws, size_t ws_size,
                              hipStream_t stream) {
  (void)in_sizes; (void)n_in; (void)out_size; (void)ws_size;
  const float* x      = (const float*)d_in[0];
  const float* emb_w  = (const float*)d_in[1];
  const float* emb_b  = (const float*)d_in[2];
  const float* inp_w  = (const float*)d_in[3];
  const float* conv_w = (const float*)d_in[4];
  const float* conv_b = (const float*)d_in[5];
  const float* xp_w   = (const float*)d_in[6];
  const float* dt_w   = (const float*)d_in[7];
  const float* dt_b   = (const float*)d_in[8];
  const float* a_log  = (const float*)d_in[9];
  const float* Dw     = (const float*)d_in[10];
  const float* outp_w = (const float*)d_in[11];
  const float* n1_w   = (const float*)d_in[12];
  const float* n2_w   = (const float*)d_in[13];
  const float* fc1_w  = (const float*)d_in[14];
  const float* fc2_w  = (const float*)d_in[15];
  const float* nf_w   = (const float*)d_in[16];
  const float* head_w = (const float*)d_in[17];
  const float* head_b = (const float*)d_in[18];

  float* fp = (float*)d_ws;
  float* resid  = fp;                 // 2048 x 512
  float* hid    = fp + 1048576;
  float* xdb    = fp + 2097152;       // T x 32 (B|C)
  float* sP     = fp + 2162688;       // 8 x 4 x 1024 x 16
  float* sH     = fp + 2686976;
  float* pooled = fp + 3211264;       // 2048
  u16* us  = (u16*)(fp + 3213312);
  u16* xzb  = us;                     // T x 2048
  u16* xb   = us + 4194304;           // 262144
  u16* xnb  = us + 4456448;           // T x 512
  u16* ygb  = us + 5505024;           // T x 1024
  u16* mlb  = us + 7602176;           // T x 2048
  u16* xcb  = us + 11796480;          // T x 1024
  u16* dtb  = us + 13893632;          // T x 1024
  u16* embh = us + 15990784;          // 512 x 128
  u16* wall = us + 16056320;          // 12 x 5,832,704

  const int O_OUTP = 1048576, O_FC1 = 1572864, O_FC2 = 3670016, O_M = 4718592;
  const size_t WSTRIDE = 5832704;

  k_prep<<<29440, 256, 0, stream>>>(x, emb_w, inp_w, outp_w, fc1_w, fc2_w, dt_w, xp_w,
                                    xb, embh, wall);
  gemm_bf<2, 1, 1, 1><<<dim3(16, 32), 256, 0, stream>>>(
      xb, 128, embh, nullptr, 128, (void*)hid, 512, 128, emb_b, nullptr);

  for (int i = 0; i < 12; ++i) {
    const u16* wL = wall + (size_t)i * WSTRIDE;
    k_addnorm<<<2048, 256, 0, stream>>>(resid, hid, n1_w + i * 512, xnb, i == 0 ? 1 : 0);
    gemm_bf<4, 2, 1, 2><<<dim3(32, 16), 256, 0, stream>>>(
        xnb, 512, wL, nullptr, 512, (void*)xzb, 2048, 512, nullptr, nullptr);
    k_conv<<<2048, 256, 0, stream>>>(xzb, conv_w + (size_t)i * 4096, conv_b + i * 1024, xcb);
    gemm_bf<2, 2, 1, 3><<<dim3(17, 32), 256, 0, stream>>>(
        xcb, 1024, wL + O_M, nullptr, 1024, (void*)dtb, 1024, 1024, dt_b + i * 1024, xdb);
    k_scan1<<<512, 256, 0, stream>>>(dtb, xcb, xdb, a_log + (size_t)i * 16384, sP, sH);
    k_scan3<<<512, 256, 0, stream>>>(dtb, xcb, xdb, a_log + (size_t)i * 16384, sP, sH,
                                     xzb, Dw + i * 1024, ygb);
    gemm_bf<2, 1, 1, 0><<<dim3(16, 32), 256, 0, stream>>>(
        ygb, 1024, wL + O_OUTP, nullptr, 1024, (void*)hid, 512, 1024, nullptr, nullptr);
    k_addnorm<<<2048, 256, 0, stream>>>(resid, hid, n2_w + i * 512, xnb, 0);
    gemm_bf<4, 2, 2, 4><<<dim3(32, 16), 256, 0, stream>>>(
        xnb, 512, wL + O_FC1, wL + O_FC1 + 1048576, 512,
        (void*)mlb, 2048, 512, nullptr, nullptr);
    gemm_bf<2, 1, 1, 0><<<dim3(16, 32), 256, 0, stream>>>(
        mlb, 2048, wL + O_FC2, nullptr, 2048, (void*)hid, 512, 2048, nullptr, nullptr);
  }

  k_addnorm<<<2048, 256, 0, stream>>>(resid, hid, nf_w, xnb, 0);
  k_pool<<<8, 256, 0, stream>>>(xnb, pooled);
  k_head<<<200, 64, 0, stream>>>(pooled, head_w, head_b, (float*)d_out);
}